// Round 1
// baseline (2784.923 us; speedup 1.0000x reference)
//
#include <hip/hip_runtime.h>
#include <hip/hip_bf16.h>
#include <math.h>

// ---------------------------------------------------------------------------
// ConvFormer: T=8 frames, Ci=1, Co=16, spatial 64^3 (=2^18 voxels/plane)
// Pipeline:
//   prep: transpose weights into ws (uniform scalar-load friendly layouts)
//   k1:   q/k/v 3x3x3 convs (Ci=1) + per-(t,co) sum/sumsq stats (atomics)
//   fin:  sums -> mean/rstd
//   k2:   per-voxel: normalize+leaky q/k/v, A=Wa1*qn, B=Wa2*kn,
//         64 frame-pairs: sigmoid(Wa3*relu(A_i+B_j)) gating, acc vn, u=acc+qn
//         (u written into d_out as scratch)
//   k3:   final 16->16 3x3x3 conv from u, + stats (writes raw conv to ws)
//   fin:  sums -> mean/rstd
//   k4:   normalize + leaky -> d_out
// ---------------------------------------------------------------------------

#define V18 (1 << 18)            // voxels per (t,co) plane
#define QKV_FLOATS (1 << 25)     // floats per q/k/v tensor (8*16*2^18)
#define SOFF (3 * QKV_FLOATS)    // stats base offset in ws (floats)

// packed-weight offsets (floats, relative to P)
#define PW_Q 0
#define PW_K 432
#define PW_V 864
#define PW_A1 1296
#define PW_A2 1552
#define PW_A3 1808
#define PW_F 2064                // [ci][tap][co], 16*27*16 = 6912

__device__ __forceinline__ float lrelu(float x) { return x > 0.f ? x : 0.2f * x; }
__device__ __forceinline__ float sigm(float x) {
  return __builtin_amdgcn_rcpf(1.f + __expf(-x));
}

// --------------------------------------------------------------------------
__global__ void k_prep(const float* __restrict__ Wq, const float* __restrict__ Wk,
                       const float* __restrict__ Wv, const float* __restrict__ Wa1,
                       const float* __restrict__ Wa2, const float* __restrict__ Wa3,
                       const float* __restrict__ Wf, float* __restrict__ P) {
  int tid = threadIdx.x;
  for (int i = tid; i < 432; i += 256) {        // W*[co][27] -> [tap][co]
    int co = i / 27, tap = i % 27;
    P[PW_Q + tap * 16 + co] = Wq[i];
    P[PW_K + tap * 16 + co] = Wk[i];
    P[PW_V + tap * 16 + co] = Wv[i];
  }
  for (int i = tid; i < 256; i += 256) {        // Wa[o][i] -> [i][o]
    int o = i >> 4, ii = i & 15;
    P[PW_A1 + ii * 16 + o] = Wa1[i];
    P[PW_A2 + ii * 16 + o] = Wa2[i];
    P[PW_A3 + ii * 16 + o] = Wa3[i];
  }
  for (int i = tid; i < 6912; i += 256) {       // Wf[co][ci][27] -> [ci][tap][co]
    int co = i / 432, r = i % 432, ci = r / 27, tap = r % 27;
    P[PW_F + (ci * 27 + tap) * 16 + co] = Wf[i];
  }
}

// --------------------------------------------------------------------------
// k1: tile (z,y,x) = (4,4,32) -> 512 voxels/block, halo (6,6,34)=1224.
__global__ __launch_bounds__(256) void k1_qkv(
    const float* __restrict__ c, const float* __restrict__ e,
    const float* __restrict__ pos, const float* __restrict__ P,
    const float* __restrict__ bq, const float* __restrict__ bk,
    const float* __restrict__ bv, float* __restrict__ q, float* __restrict__ k,
    float* __restrict__ v, float* __restrict__ stats) {
  __shared__ float se[1224], sc[1224];
  __shared__ float red[96];
  const int t = blockIdx.y;
  const int tile = blockIdx.x;              // 512 = 16z * 16y * 2x
  const int x0 = (tile & 1) * 32;
  const int y0 = ((tile >> 1) & 15) * 4;
  const int z0 = (tile >> 5) * 4;
  const float* cin = c + t * V18;
  const float* ein = e + t * V18;
  for (int i = threadIdx.x; i < 1224; i += 256) {
    int lz = i / 204, r = i % 204, ly = r / 34, lx = r % 34;
    int gz = z0 + lz - 1, gy = y0 + ly - 1, gx = x0 + lx - 1;
    float pe = 0.f, pc = 0.f;
    if ((unsigned)gz < 64u && (unsigned)gy < 64u && (unsigned)gx < 64u) {
      int gi = (gz << 12) + (gy << 6) + gx;
      float pv = pos[gi];
      pc = cin[gi] + pv;
      pe = ein[gi] + pv;
    }
    se[i] = pe;
    sc[i] = pc;
  }
  if (threadIdx.x < 96) red[threadIdx.x] = 0.f;
  __syncthreads();

  const int lane = threadIdx.x & 63;
  for (int s2 = 0; s2 < 2; ++s2) {
    int li = threadIdx.x + s2 * 256;        // 512 voxels: 4z*4y*32x
    int lz = li >> 7, ly = (li >> 5) & 3, lx = li & 31;
    float xe[27], xc[27];
#pragma unroll
    for (int dz = 0; dz < 3; ++dz)
#pragma unroll
      for (int dy = 0; dy < 3; ++dy)
#pragma unroll
        for (int dx = 0; dx < 3; ++dx) {
          int a = ((lz + dz) * 6 + (ly + dy)) * 34 + (lx + dx);
          int tt = (dz * 3 + dy) * 3 + dx;
          xe[tt] = se[a];
          xc[tt] = sc[a];
        }
    int gi = ((z0 + lz) << 12) + ((y0 + ly) << 6) + (x0 + lx);
#pragma unroll
    for (int co = 0; co < 16; ++co) {
      float oq = bq[co], ok = bk[co], ov = bv[co];
#pragma unroll
      for (int tap = 0; tap < 27; ++tap) {
        oq += P[PW_Q + tap * 16 + co] * xe[tap];
        ok += P[PW_K + tap * 16 + co] * xc[tap];
        ov += P[PW_V + tap * 16 + co] * xc[tap];
      }
      q[((t * 16 + co) << 18) + gi] = oq;
      k[((t * 16 + co) << 18) + gi] = ok;
      v[((t * 16 + co) << 18) + gi] = ov;
      float s_[6] = {oq, oq * oq, ok, ok * ok, ov, ov * ov};
#pragma unroll
      for (int u_ = 0; u_ < 6; ++u_) {
        float r1 = s_[u_];
#pragma unroll
        for (int d = 32; d > 0; d >>= 1) r1 += __shfl_xor(r1, d);
        if (lane == 0) atomicAdd(&red[(u_ >> 1) * 32 + co * 2 + (u_ & 1)], r1);
      }
    }
  }
  __syncthreads();
  if (threadIdx.x < 96) {
    int cv = threadIdx.x >> 5;     // conv type 0..2
    int rem = threadIdx.x & 31;    // co*2 + sidx
    atomicAdd(&stats[(cv * 8 + t) * 32 + rem], red[threadIdx.x]);
  }
}

// --------------------------------------------------------------------------
__global__ void k_finstats(const float* __restrict__ sums, float* __restrict__ mr,
                           int n, float invn) {
  int i = blockIdx.x * blockDim.x + threadIdx.x;
  if (i >= n) return;
  float m = sums[i * 2] * invn;
  float var = sums[i * 2 + 1] * invn - m * m;
  mr[i * 2] = m;
  mr[i * 2 + 1] = rsqrtf(fmaxf(var, 0.f) + 1e-5f);
}

// --------------------------------------------------------------------------
// k2: one thread per voxel; frames split into 2 halves of 4 to bound VGPRs.
__global__ __launch_bounds__(256) void k2_attn(
    const float* __restrict__ q, const float* __restrict__ k,
    const float* __restrict__ v, const float* __restrict__ P,
    const float* __restrict__ mr, const float* __restrict__ ba1,
    const float* __restrict__ ba2, const float* __restrict__ ba3,
    float* __restrict__ u) {
  const int x = blockIdx.x * 256 + threadIdx.x;
#pragma unroll 1
  for (int half = 0; half < 2; ++half) {
    float A[4][16], acc[4][16];
#pragma unroll
    for (int i = 0; i < 4; ++i) {
      const int t = half * 4 + i;
      float qn[16];
#pragma unroll
      for (int co = 0; co < 16; ++co) {
        float raw = q[((t * 16 + co) << 18) + x];
        qn[co] = lrelu((raw - mr[(t * 16 + co) * 2]) * mr[(t * 16 + co) * 2 + 1]);
      }
#pragma unroll
      for (int o = 0; o < 16; ++o) {
        A[i][o] = ba1[o];
        acc[i][o] = 0.f;
      }
#pragma unroll
      for (int ii = 0; ii < 16; ++ii)
#pragma unroll
        for (int o = 0; o < 16; ++o) A[i][o] += P[PW_A1 + ii * 16 + o] * qn[ii];
    }
#pragma unroll 1
    for (int j = 0; j < 8; ++j) {
      float kn[16], vn[16], B[16];
#pragma unroll
      for (int co = 0; co < 16; ++co) {
        float rk = k[((j * 16 + co) << 18) + x];
        float rv = v[((j * 16 + co) << 18) + x];
        kn[co] = lrelu((rk - mr[256 + (j * 16 + co) * 2]) * mr[256 + (j * 16 + co) * 2 + 1]);
        vn[co] = lrelu((rv - mr[512 + (j * 16 + co) * 2]) * mr[512 + (j * 16 + co) * 2 + 1]);
      }
#pragma unroll
      for (int o = 0; o < 16; ++o) B[o] = ba2[o];
#pragma unroll
      for (int ii = 0; ii < 16; ++ii)
#pragma unroll
        for (int o = 0; o < 16; ++o) B[o] += P[PW_A2 + ii * 16 + o] * kn[ii];
#pragma unroll
      for (int i = 0; i < 4; ++i) {
        float s[16];
#pragma unroll
        for (int o = 0; o < 16; ++o) s[o] = ba3[o];
#pragma unroll
        for (int ii = 0; ii < 16; ++ii) {
          float r = fmaxf(A[i][ii] + B[ii], 0.f);
#pragma unroll
          for (int o = 0; o < 16; ++o) s[o] += P[PW_A3 + ii * 16 + o] * r;
        }
#pragma unroll
        for (int o = 0; o < 16; ++o) acc[i][o] += sigm(s[o]) * vn[o];
      }
    }
#pragma unroll
    for (int i = 0; i < 4; ++i) {
      const int t = half * 4 + i;
#pragma unroll
      for (int co = 0; co < 16; ++co) {
        float raw = q[((t * 16 + co) << 18) + x];
        float qn = lrelu((raw - mr[(t * 16 + co) * 2]) * mr[(t * 16 + co) * 2 + 1]);
        u[((t * 16 + co) << 18) + x] = acc[i][co] + qn;
      }
    }
  }
}

// --------------------------------------------------------------------------
// k3: final conv 16->16. tile (2,4,32)=256 voxels, halo (4,6,34)=816/ci.
__global__ __launch_bounds__(256) void k3_conv(
    const float* __restrict__ u, const float* __restrict__ P,
    const float* __restrict__ bf, float* __restrict__ y,
    float* __restrict__ fstats) {
  __shared__ float sx[16 * 816];
  __shared__ float red[32];
  const int t = blockIdx.y;
  const int tile = blockIdx.x;              // 1024 = 32z * 16y * 2x
  const int x0 = (tile & 1) * 32;
  const int y0 = ((tile >> 1) & 15) * 4;
  const int z0 = (tile >> 5) * 2;
  for (int i = threadIdx.x; i < 16 * 816; i += 256) {
    int ci = i / 816, r = i % 816;
    int lz = r / 204, r2 = r % 204, ly = r2 / 34, lx = r2 % 34;
    int gz = z0 + lz - 1, gy = y0 + ly - 1, gx = x0 + lx - 1;
    float val = 0.f;
    if ((unsigned)gz < 64u && (unsigned)gy < 64u && (unsigned)gx < 64u)
      val = u[((t * 16 + ci) << 18) + (gz << 12) + (gy << 6) + gx];
    sx[i] = val;
  }
  if (threadIdx.x < 32) red[threadIdx.x] = 0.f;
  __syncthreads();

  const int lz = threadIdx.x >> 7, ly = (threadIdx.x >> 5) & 3, lx = threadIdx.x & 31;
  float acc[16];
#pragma unroll
  for (int co = 0; co < 16; ++co) acc[co] = bf[co];
#pragma unroll 1
  for (int ci = 0; ci < 16; ++ci) {
    const float* sp = sx + ci * 816;
    const float* wp = P + PW_F + ci * 432;  // [tap][co]
#pragma unroll
    for (int dz = 0; dz < 3; ++dz)
#pragma unroll
      for (int dy = 0; dy < 3; ++dy)
#pragma unroll
        for (int dx = 0; dx < 3; ++dx) {
          float xv = sp[((lz + dz) * 6 + (ly + dy)) * 34 + (lx + dx)];
          const int tap = (dz * 3 + dy) * 3 + dx;
#pragma unroll
          for (int co = 0; co < 16; ++co) acc[co] += wp[tap * 16 + co] * xv;
        }
  }
  const int gi = ((z0 + lz) << 12) + ((y0 + ly) << 6) + (x0 + lx);
  const int lane = threadIdx.x & 63;
#pragma unroll
  for (int co = 0; co < 16; ++co) {
    y[((t * 16 + co) << 18) + gi] = acc[co];
    float r1 = acc[co], r2 = acc[co] * acc[co];
#pragma unroll
    for (int d = 32; d > 0; d >>= 1) {
      r1 += __shfl_xor(r1, d);
      r2 += __shfl_xor(r2, d);
    }
    if (lane == 0) {
      atomicAdd(&red[co * 2], r1);
      atomicAdd(&red[co * 2 + 1], r2);
    }
  }
  __syncthreads();
  if (threadIdx.x < 32) atomicAdd(&fstats[t * 32 + threadIdx.x], red[threadIdx.x]);
}

// --------------------------------------------------------------------------
__global__ __launch_bounds__(256) void k4_norm(const float* __restrict__ y,
                                               const float* __restrict__ fmr,
                                               float* __restrict__ out) {
  int tid = blockIdx.x * 256 + threadIdx.x;
#pragma unroll 1
  for (int it = 0; it < 8; ++it) {
    int i4 = tid + it * 1048576;            // float4 index; 8,388,608 total
    int plane = (i4 << 2) >> 18;            // t*16+co
    float m = fmr[plane * 2], rs = fmr[plane * 2 + 1];
    float4 val = reinterpret_cast<const float4*>(y)[i4];
    float4 o;
    o.x = lrelu((val.x - m) * rs);
    o.y = lrelu((val.y - m) * rs);
    o.z = lrelu((val.z - m) * rs);
    o.w = lrelu((val.w - m) * rs);
    reinterpret_cast<float4*>(out)[i4] = o;
  }
}

// --------------------------------------------------------------------------
extern "C" void kernel_launch(void* const* d_in, const int* in_sizes, int n_in,
                              void* d_out, int out_size, void* d_ws, size_t ws_size,
                              hipStream_t stream) {
  const float* c = (const float*)d_in[0];
  const float* e = (const float*)d_in[1];
  const float* pos = (const float*)d_in[2];
  const float* Wq = (const float*)d_in[3];
  const float* bq = (const float*)d_in[4];
  const float* Wk = (const float*)d_in[5];
  const float* bk = (const float*)d_in[6];
  const float* Wv = (const float*)d_in[7];
  const float* bv = (const float*)d_in[8];
  const float* Wa1 = (const float*)d_in[9];
  const float* ba1 = (const float*)d_in[10];
  const float* Wa2 = (const float*)d_in[11];
  const float* ba2 = (const float*)d_in[12];
  const float* Wa3 = (const float*)d_in[13];
  const float* ba3 = (const float*)d_in[14];
  const float* Wf = (const float*)d_in[15];
  const float* bf_ = (const float*)d_in[16];

  float* ws = (float*)d_ws;
  float* q = ws;
  float* k = ws + QKV_FLOATS;
  float* v = ws + 2 * QKV_FLOATS;
  float* y = ws;                   // aliases q (q dead after k2)
  float* stats = ws + SOFF;        // qkv sums: 768 floats
  float* fsums = stats + 768;      // 256
  float* qkvmr = stats + 1024;     // 768
  float* fmr = stats + 1792;       // 256
  float* P = stats + 2048;         // 8976 packed weights
  float* uo = (float*)d_out;       // u scratch, then final output

  hipMemsetAsync(stats, 0, 1024 * sizeof(float), stream);
  hipLaunchKernelGGL(k_prep, dim3(1), dim3(256), 0, stream,
                     Wq, Wk, Wv, Wa1, Wa2, Wa3, Wf, P);
  hipLaunchKernelGGL(k1_qkv, dim3(512, 8), dim3(256), 0, stream,
                     c, e, pos, P, bq, bk, bv, q, k, v, stats);
  hipLaunchKernelGGL(k_finstats, dim3(2), dim3(256), 0, stream,
                     stats, qkvmr, 384, 1.f / 262144.f);
  hipLaunchKernelGGL(k2_attn, dim3(1024), dim3(256), 0, stream,
                     q, k, v, P, qkvmr, ba1, ba2, ba3, uo);
  hipLaunchKernelGGL(k3_conv, dim3(1024, 8), dim3(256), 0, stream,
                     uo, P, bf_, y, fsums);
  hipLaunchKernelGGL(k_finstats, dim3(1), dim3(256), 0, stream,
                     fsums, fmr, 128, 1.f / 262144.f);
  hipLaunchKernelGGL(k4_norm, dim3(4096), dim3(256), 0, stream, y, fmr, uo);
}

// Round 2
// 1485.160 us; speedup vs baseline: 1.8752x; 1.8752x over previous
//
#include <hip/hip_runtime.h>
#include <hip/hip_bf16.h>
#include <math.h>

// ---------------------------------------------------------------------------
// ConvFormer: T=8, Ci=1, Co=16, spatial 64^3.
//   k_prep:  repack weights into ws
//   k1_qkv:  q/k/v 3x3x3 convs (pure conv, weights in LDS, 4 vox/thread)
//   kstats:  per-(plane) sum/sumsq (memory-bound pass)
//   k_finstats: sums -> mean/rstd
//   k2_attn: normalize+leaky, channel-mix linears, 8x8 frame gating -> u (d_out)
//   k3_conv: final 16->16 conv, ci-chunked LDS staging, no stats
//   kstats + k_finstats on y
//   k4_norm: normalize + leaky -> d_out
// ---------------------------------------------------------------------------

#define V18 (1 << 18)
#define QKV_FLOATS (1 << 25)
#define SOFF (3 * QKV_FLOATS)

// packed weights (floats, relative to P)
// [0,1344): qkv conv [conv][co][28] (tap padded 27->28)
#define PW_A1 1344
#define PW_A2 1600
#define PW_A3 1856
#define PW_F 2112   // [ci][tap][co] : 16*27*16 = 6912

#define COMP(v, j) ((j) == 0 ? (v).x : (j) == 1 ? (v).y : (j) == 2 ? (v).z : (v).w)

__device__ __forceinline__ float lrelu(float x) { return x > 0.f ? x : 0.2f * x; }
__device__ __forceinline__ float sigm(float x) {
  return __builtin_amdgcn_rcpf(1.f + __expf(-x));
}

// --------------------------------------------------------------------------
__global__ void k_prep(const float* __restrict__ Wq, const float* __restrict__ Wk,
                       const float* __restrict__ Wv, const float* __restrict__ Wa1,
                       const float* __restrict__ Wa2, const float* __restrict__ Wa3,
                       const float* __restrict__ Wf, float* __restrict__ P) {
  int tid = threadIdx.x;
  for (int i = tid; i < 1344; i += 256) {        // [conv][co][28]
    int conv = i / 448, r = i % 448, co = r / 28, tap = r % 28;
    const float* W = conv == 0 ? Wq : conv == 1 ? Wk : Wv;
    P[i] = (tap < 27) ? W[co * 27 + tap] : 0.f;
  }
  for (int i = tid; i < 256; i += 256) {         // Wa[o][i] -> [i][o]
    int o = i >> 4, ii = i & 15;
    P[PW_A1 + ii * 16 + o] = Wa1[i];
    P[PW_A2 + ii * 16 + o] = Wa2[i];
    P[PW_A3 + ii * 16 + o] = Wa3[i];
  }
  for (int i = tid; i < 6912; i += 256) {        // Wf[co][ci][27] -> [ci][tap][co]
    int co = i / 432, r = i % 432, ci = r / 27, tap = r % 27;
    P[PW_F + (ci * 27 + tap) * 16 + co] = Wf[i];
  }
}

// --------------------------------------------------------------------------
// k1: tile (z,y,x)=(4,4,64), 1024 voxels, 4 consecutive-x per thread.
// Halo (6,6,66) stored with row stride 68 (16B-aligned b128 reads).
__global__ __launch_bounds__(256) void k1_qkv(
    const float* __restrict__ c, const float* __restrict__ e,
    const float* __restrict__ pos, const float* __restrict__ P,
    const float* __restrict__ bq, const float* __restrict__ bk,
    const float* __restrict__ bv, float* __restrict__ q,
    float* __restrict__ k, float* __restrict__ v) {
  __shared__ __align__(16) float se[2448];   // 6*6*68
  __shared__ __align__(16) float sc[2448];
  __shared__ __align__(16) float wl[1344];
  const int t = blockIdx.y;
  const int tile = blockIdx.x;               // 256 = 16z * 16y
  const int y0 = (tile & 15) * 4;
  const int z0 = (tile >> 4) * 4;
  for (int i = threadIdx.x; i < 1344; i += 256) wl[i] = P[i];
  const float* cin = c + t * V18;
  const float* ein = e + t * V18;
  for (int i = threadIdx.x; i < 2448; i += 256) {
    int lz = i / 408, r = i % 408, ly = r / 68, lx = r % 68;
    int gz = z0 + lz - 1, gy = y0 + ly - 1, gx = lx - 1;
    float pe = 0.f, pc = 0.f;
    if (lx < 66 && (unsigned)gz < 64u && (unsigned)gy < 64u && (unsigned)gx < 64u) {
      int gi = (gz << 12) + (gy << 6) + gx;
      float pv = pos[gi];
      pc = cin[gi] + pv;
      pe = ein[gi] + pv;
    }
    se[i] = pe;
    sc[i] = pc;
  }
  __syncthreads();

  const int lz = threadIdx.x >> 6, ly = (threadIdx.x >> 4) & 3,
            lx = (threadIdx.x & 15) * 4;
  const int gi = ((z0 + lz) << 12) + ((y0 + ly) << 6) + lx;

  // ---- pass 1: q (input e) ----
  {
    float xr[3][3][6];
#pragma unroll
    for (int dz = 0; dz < 3; ++dz)
#pragma unroll
      for (int dy = 0; dy < 3; ++dy) {
        int base = ((lz + dz) * 6 + (ly + dy)) * 68 + lx;
        float4 a = *(const float4*)&se[base];
        float2 b2 = *(const float2*)&se[base + 4];
        xr[dz][dy][0] = a.x; xr[dz][dy][1] = a.y; xr[dz][dy][2] = a.z;
        xr[dz][dy][3] = a.w; xr[dz][dy][4] = b2.x; xr[dz][dy][5] = b2.y;
      }
#pragma unroll 1
    for (int co = 0; co < 16; ++co) {
      float bias = bq[co];
      float4 acc = {bias, bias, bias, bias};
      const float* wp = &wl[co * 28];
#pragma unroll
      for (int tg = 0; tg < 7; ++tg) {
        float4 w4 = *(const float4*)&wp[tg * 4];
#pragma unroll
        for (int j = 0; j < 4; ++j) {
          const int tap = tg * 4 + j;
          if (tap < 27) {
            const int dz = tap / 9, dy = (tap / 3) % 3, dx = tap % 3;
            float w = COMP(w4, j);
            acc.x += w * xr[dz][dy][dx + 0];
            acc.y += w * xr[dz][dy][dx + 1];
            acc.z += w * xr[dz][dy][dx + 2];
            acc.w += w * xr[dz][dy][dx + 3];
          }
        }
      }
      *(float4*)&q[((t * 16 + co) << 18) + gi] = acc;
    }
  }
  // ---- pass 2: k, v (input c) ----
  {
    float xr[3][3][6];
#pragma unroll
    for (int dz = 0; dz < 3; ++dz)
#pragma unroll
      for (int dy = 0; dy < 3; ++dy) {
        int base = ((lz + dz) * 6 + (ly + dy)) * 68 + lx;
        float4 a = *(const float4*)&sc[base];
        float2 b2 = *(const float2*)&sc[base + 4];
        xr[dz][dy][0] = a.x; xr[dz][dy][1] = a.y; xr[dz][dy][2] = a.z;
        xr[dz][dy][3] = a.w; xr[dz][dy][4] = b2.x; xr[dz][dy][5] = b2.y;
      }
#pragma unroll 1
    for (int co = 0; co < 16; ++co) {
      float bk_ = bk[co], bv_ = bv[co];
      float4 ak = {bk_, bk_, bk_, bk_};
      float4 av = {bv_, bv_, bv_, bv_};
      const float* wpk = &wl[448 + co * 28];
      const float* wpv = &wl[896 + co * 28];
#pragma unroll
      for (int tg = 0; tg < 7; ++tg) {
        float4 wk4 = *(const float4*)&wpk[tg * 4];
        float4 wv4 = *(const float4*)&wpv[tg * 4];
#pragma unroll
        for (int j = 0; j < 4; ++j) {
          const int tap = tg * 4 + j;
          if (tap < 27) {
            const int dz = tap / 9, dy = (tap / 3) % 3, dx = tap % 3;
            float wk_ = COMP(wk4, j), wv_ = COMP(wv4, j);
            ak.x += wk_ * xr[dz][dy][dx + 0];
            ak.y += wk_ * xr[dz][dy][dx + 1];
            ak.z += wk_ * xr[dz][dy][dx + 2];
            ak.w += wk_ * xr[dz][dy][dx + 3];
            av.x += wv_ * xr[dz][dy][dx + 0];
            av.y += wv_ * xr[dz][dy][dx + 1];
            av.z += wv_ * xr[dz][dy][dx + 2];
            av.w += wv_ * xr[dz][dy][dx + 3];
          }
        }
      }
      *(float4*)&k[((t * 16 + co) << 18) + gi] = ak;
      *(float4*)&v[((t * 16 + co) << 18) + gi] = av;
    }
  }
}

// --------------------------------------------------------------------------
// kstats: grid (8, planes); each block sums 32768 floats of one plane.
__global__ __launch_bounds__(256) void kstats(const float* __restrict__ src,
                                              float* __restrict__ sums) {
  const int plane = blockIdx.y;
  const float4* s4 = (const float4*)src + (plane << 16) + (blockIdx.x << 13) +
                     threadIdx.x;
  float s = 0.f, s2 = 0.f;
#pragma unroll
  for (int j = 0; j < 32; ++j) {
    float4 val = s4[j * 256];
    s += val.x + val.y + val.z + val.w;
    s2 += val.x * val.x + val.y * val.y + val.z * val.z + val.w * val.w;
  }
#pragma unroll
  for (int d = 32; d > 0; d >>= 1) {
    s += __shfl_xor(s, d);
    s2 += __shfl_xor(s2, d);
  }
  __shared__ float rs[8];
  const int wid = threadIdx.x >> 6;
  if ((threadIdx.x & 63) == 0) {
    rs[wid] = s;
    rs[4 + wid] = s2;
  }
  __syncthreads();
  if (threadIdx.x == 0) {
    atomicAdd(&sums[plane * 2], rs[0] + rs[1] + rs[2] + rs[3]);
    atomicAdd(&sums[plane * 2 + 1], rs[4] + rs[5] + rs[6] + rs[7]);
  }
}

// --------------------------------------------------------------------------
__global__ void k_finstats(const float* __restrict__ sums, float* __restrict__ mr,
                           int n, float invn) {
  int i = blockIdx.x * blockDim.x + threadIdx.x;
  if (i >= n) return;
  float m = sums[i * 2] * invn;
  float var = sums[i * 2 + 1] * invn - m * m;
  mr[i * 2] = m;
  mr[i * 2 + 1] = rsqrtf(fmaxf(var, 0.f) + 1e-5f);
}

// --------------------------------------------------------------------------
__global__ __launch_bounds__(256) void k2_attn(
    const float* __restrict__ q, const float* __restrict__ k,
    const float* __restrict__ v, const float* __restrict__ P,
    const float* __restrict__ mr, const float* __restrict__ ba1,
    const float* __restrict__ ba2, const float* __restrict__ ba3,
    float* __restrict__ u) {
  const int x = blockIdx.x * 256 + threadIdx.x;
#pragma unroll 1
  for (int half = 0; half < 2; ++half) {
    float A[4][16], acc[4][16];
#pragma unroll
    for (int i = 0; i < 4; ++i) {
      const int t = half * 4 + i;
      float qn[16];
#pragma unroll
      for (int co = 0; co < 16; ++co) {
        float raw = q[((t * 16 + co) << 18) + x];
        qn[co] = lrelu((raw - mr[(t * 16 + co) * 2]) * mr[(t * 16 + co) * 2 + 1]);
      }
#pragma unroll
      for (int o = 0; o < 16; ++o) {
        A[i][o] = ba1[o];
        acc[i][o] = 0.f;
      }
#pragma unroll
      for (int ii = 0; ii < 16; ++ii)
#pragma unroll
        for (int o = 0; o < 16; ++o) A[i][o] += P[PW_A1 + ii * 16 + o] * qn[ii];
    }
#pragma unroll 1
    for (int j = 0; j < 8; ++j) {
      float kn[16], vn[16], B[16];
#pragma unroll
      for (int co = 0; co < 16; ++co) {
        float rk = k[((j * 16 + co) << 18) + x];
        float rv = v[((j * 16 + co) << 18) + x];
        kn[co] = lrelu((rk - mr[256 + (j * 16 + co) * 2]) * mr[256 + (j * 16 + co) * 2 + 1]);
        vn[co] = lrelu((rv - mr[512 + (j * 16 + co) * 2]) * mr[512 + (j * 16 + co) * 2 + 1]);
      }
#pragma unroll
      for (int o = 0; o < 16; ++o) B[o] = ba2[o];
#pragma unroll
      for (int ii = 0; ii < 16; ++ii)
#pragma unroll
        for (int o = 0; o < 16; ++o) B[o] += P[PW_A2 + ii * 16 + o] * kn[ii];
#pragma unroll
      for (int i = 0; i < 4; ++i) {
        float s[16];
#pragma unroll
        for (int o = 0; o < 16; ++o) s[o] = ba3[o];
#pragma unroll
        for (int ii = 0; ii < 16; ++ii) {
          float r = fmaxf(A[i][ii] + B[ii], 0.f);
#pragma unroll
          for (int o = 0; o < 16; ++o) s[o] += P[PW_A3 + ii * 16 + o] * r;
        }
#pragma unroll
        for (int o = 0; o < 16; ++o) acc[i][o] += sigm(s[o]) * vn[o];
      }
    }
#pragma unroll
    for (int i = 0; i < 4; ++i) {
      const int t = half * 4 + i;
#pragma unroll
      for (int co = 0; co < 16; ++co) {
        float raw = q[((t * 16 + co) << 18) + x];
        float qn = lrelu((raw - mr[(t * 16 + co) * 2]) * mr[(t * 16 + co) * 2 + 1]);
        u[((t * 16 + co) << 18) + x] = acc[i][co] + qn;
      }
    }
  }
}

// --------------------------------------------------------------------------
// k3: tile (z,y,x)=(2,8,64), 1024 voxels, 4 consecutive-x per thread.
// ci processed in 4 chunks of 4; per-chunk halo (4,10,66->68) + weights in LDS.
__global__ __launch_bounds__(256) void k3_conv(
    const float* __restrict__ u, const float* __restrict__ P,
    const float* __restrict__ bfv, float* __restrict__ y) {
  __shared__ __align__(16) float sx[4 * 2720];  // 4 ci * (4*10*68)
  __shared__ __align__(16) float wf[1728];      // 4 ci * 27 tap * 16 co
  const int t = blockIdx.y;
  const int tile = blockIdx.x;                  // 256 = 32z * 8y
  const int y0 = (tile & 7) * 8;
  const int z0 = (tile >> 3) * 2;
  const int lz = threadIdx.x >> 7, ly = (threadIdx.x >> 4) & 7,
            lx = (threadIdx.x & 15) * 4;
  const int gi = ((z0 + lz) << 12) + ((y0 + ly) << 6) + lx;

  float acc[16][4];
#pragma unroll
  for (int co = 0; co < 16; ++co) {
    float b = bfv[co];
    acc[co][0] = b; acc[co][1] = b; acc[co][2] = b; acc[co][3] = b;
  }

#pragma unroll 1
  for (int cig = 0; cig < 4; ++cig) {
    __syncthreads();
    for (int i = threadIdx.x; i < 4 * 2720; i += 256) {
      int ci_l = i / 2720, r = i % 2720;
      int lzz = r / 680, r2 = r % 680, lyy = r2 / 68, lxx = r2 % 68;
      int gz = z0 + lzz - 1, gy = y0 + lyy - 1, gx = lxx - 1;
      float val = 0.f;
      if (lxx < 66 && (unsigned)gz < 64u && (unsigned)gy < 64u && (unsigned)gx < 64u)
        val = u[((t * 16 + cig * 4 + ci_l) << 18) + (gz << 12) + (gy << 6) + gx];
      sx[i] = val;
    }
    for (int i = threadIdx.x; i < 1728; i += 256)
      wf[i] = P[PW_F + cig * 1728 + i];
    __syncthreads();

#pragma unroll 1
    for (int ci_l = 0; ci_l < 4; ++ci_l) {
      float xr[3][3][6];
      const float* sp = sx + ci_l * 2720;
#pragma unroll
      for (int dz = 0; dz < 3; ++dz)
#pragma unroll
        for (int dy = 0; dy < 3; ++dy) {
          int base = ((lz + dz) * 10 + (ly + dy)) * 68 + lx;
          float4 a = *(const float4*)&sp[base];
          float2 b2 = *(const float2*)&sp[base + 4];
          xr[dz][dy][0] = a.x; xr[dz][dy][1] = a.y; xr[dz][dy][2] = a.z;
          xr[dz][dy][3] = a.w; xr[dz][dy][4] = b2.x; xr[dz][dy][5] = b2.y;
        }
      const float* wbase = &wf[ci_l * 432];
#pragma unroll
      for (int tap = 0; tap < 27; ++tap) {
        const int dz = tap / 9, dy = (tap / 3) % 3, dx = tap % 3;
        float4 w0 = *(const float4*)&wbase[tap * 16 + 0];
        float4 w1 = *(const float4*)&wbase[tap * 16 + 4];
        float4 w2 = *(const float4*)&wbase[tap * 16 + 8];
        float4 w3 = *(const float4*)&wbase[tap * 16 + 12];
        float xv0 = xr[dz][dy][dx + 0], xv1 = xr[dz][dy][dx + 1];
        float xv2 = xr[dz][dy][dx + 2], xv3 = xr[dz][dy][dx + 3];
#pragma unroll
        for (int co = 0; co < 16; ++co) {
          float w = COMP((co < 4 ? w0 : co < 8 ? w1 : co < 12 ? w2 : w3), co & 3);
          acc[co][0] += w * xv0;
          acc[co][1] += w * xv1;
          acc[co][2] += w * xv2;
          acc[co][3] += w * xv3;
        }
      }
    }
  }
#pragma unroll
  for (int co = 0; co < 16; ++co) {
    float4 o = {acc[co][0], acc[co][1], acc[co][2], acc[co][3]};
    *(float4*)&y[((t * 16 + co) << 18) + gi] = o;
  }
}

// --------------------------------------------------------------------------
__global__ __launch_bounds__(256) void k4_norm(const float* __restrict__ y,
                                               const float* __restrict__ fmr,
                                               float* __restrict__ out) {
  int tid = blockIdx.x * 256 + threadIdx.x;
#pragma unroll 1
  for (int it = 0; it < 8; ++it) {
    int i4 = tid + it * 1048576;
    int plane = (i4 << 2) >> 18;
    float m = fmr[plane * 2], rs = fmr[plane * 2 + 1];
    float4 val = reinterpret_cast<const float4*>(y)[i4];
    float4 o;
    o.x = lrelu((val.x - m) * rs);
    o.y = lrelu((val.y - m) * rs);
    o.z = lrelu((val.z - m) * rs);
    o.w = lrelu((val.w - m) * rs);
    reinterpret_cast<float4*>(out)[i4] = o;
  }
}

// --------------------------------------------------------------------------
extern "C" void kernel_launch(void* const* d_in, const int* in_sizes, int n_in,
                              void* d_out, int out_size, void* d_ws, size_t ws_size,
                              hipStream_t stream) {
  const float* c = (const float*)d_in[0];
  const float* e = (const float*)d_in[1];
  const float* pos = (const float*)d_in[2];
  const float* Wq = (const float*)d_in[3];
  const float* bq = (const float*)d_in[4];
  const float* Wk = (const float*)d_in[5];
  const float* bk = (const float*)d_in[6];
  const float* Wv = (const float*)d_in[7];
  const float* bv = (const float*)d_in[8];
  const float* Wa1 = (const float*)d_in[9];
  const float* ba1 = (const float*)d_in[10];
  const float* Wa2 = (const float*)d_in[11];
  const float* ba2 = (const float*)d_in[12];
  const float* Wa3 = (const float*)d_in[13];
  const float* ba3 = (const float*)d_in[14];
  const float* Wf = (const float*)d_in[15];
  const float* bf_ = (const float*)d_in[16];

  float* ws = (float*)d_ws;
  float* q = ws;
  float* k = ws + QKV_FLOATS;
  float* v = ws + 2 * QKV_FLOATS;
  float* y = ws;                   // aliases q (dead after k2)
  float* stats = ws + SOFF;        // qkv sums: 768
  float* fsums = stats + 768;      // 256
  float* qkvmr = stats + 1024;     // 768
  float* fmr = stats + 1792;       // 256
  float* P = stats + 2048;         // packed weights (9024)
  float* uo = (float*)d_out;

  hipMemsetAsync(stats, 0, 1024 * sizeof(float), stream);
  hipLaunchKernelGGL(k_prep, dim3(1), dim3(256), 0, stream,
                     Wq, Wk, Wv, Wa1, Wa2, Wa3, Wf, P);
  hipLaunchKernelGGL(k1_qkv, dim3(256, 8), dim3(256), 0, stream,
                     c, e, pos, P, bq, bk, bv, q, k, v);
  hipLaunchKernelGGL(kstats, dim3(8, 384), dim3(256), 0, stream, q, stats);
  hipLaunchKernelGGL(k_finstats, dim3(2), dim3(256), 0, stream,
                     stats, qkvmr, 384, 1.f / 262144.f);
  hipLaunchKernelGGL(k2_attn, dim3(1024), dim3(256), 0, stream,
                     q, k, v, P, qkvmr, ba1, ba2, ba3, uo);
  hipLaunchKernelGGL(k3_conv, dim3(256, 8), dim3(256), 0, stream,
                     uo, P, bf_, y);
  hipLaunchKernelGGL(kstats, dim3(8, 128), dim3(256), 0, stream, y, fsums);
  hipLaunchKernelGGL(k_finstats, dim3(1), dim3(256), 0, stream,
                     fsums, fmr, 128, 1.f / 262144.f);
  hipLaunchKernelGGL(k4_norm, dim3(4096), dim3(256), 0, stream, y, fmr, uo);
}

// Round 3
// 869.282 us; speedup vs baseline: 3.2037x; 1.7085x over previous
//
#include <hip/hip_runtime.h>
#include <hip/hip_bf16.h>
#include <math.h>

// ---------------------------------------------------------------------------
// ConvFormer: T=8, Ci=1, Co=16, spatial 64^3.
//   k_prep:  repack conv weights into ws
//   k1_qkv:  q/k/v 3x3x3 convs (weights in LDS, 4 vox/thread)
//   kstats:  per-plane sum/sumsq -> k_finstats: mean/rstd
//   k2_attn: MFMA gating. Per wave: 16 voxels (lane&15), channel quad
//            c=(lane>>4)*4+r. Swapped-operand mfma_16x16x16_f16 keeps this
//            layout through A=Wa1*qn, B=Wa2*kn, s=Wa3*relu(A+B). u -> d_out.
//   k3_conv: final 16->16 conv (fp32 VALU, ci-chunked LDS)
//   kstats + k_finstats on y;  k4_norm -> d_out
// ---------------------------------------------------------------------------

#define V18 (1 << 18)
#define QKV_FLOATS (1 << 25)
#define SOFF (3 * QKV_FLOATS)

#define PW_A1 1344
#define PW_A2 1600
#define PW_A3 1856
#define PW_F 2112   // [ci][tap][co] : 16*27*16 = 6912

#define COMP(v, j) ((j) == 0 ? (v).x : (j) == 1 ? (v).y : (j) == 2 ? (v).z : (v).w)

typedef __attribute__((ext_vector_type(4))) _Float16 f16x4;
typedef __attribute__((ext_vector_type(4))) float f32x4;

__device__ __forceinline__ float lrelu(float x) { return x > 0.f ? x : 0.2f * x; }
__device__ __forceinline__ float sigm(float x) {
  return __builtin_amdgcn_rcpf(1.f + __expf(-x));
}

__device__ __forceinline__ f32x4 mfma16(f16x4 a, f16x4 b, f32x4 c) {
#if defined(__has_builtin)
#if __has_builtin(__builtin_amdgcn_mfma_f32_16x16x16f16)
  return __builtin_amdgcn_mfma_f32_16x16x16f16(a, b, c, 0, 0, 0);
#else
  f32x4 d;
  asm volatile("v_mfma_f32_16x16x16_f16 %0, %1, %2, %3\n\ts_nop 7\n\ts_nop 7"
               : "=&v"(d) : "v"(a), "v"(b), "v"(c));
  return d;
#endif
#else
  f32x4 d;
  asm volatile("v_mfma_f32_16x16x16_f16 %0, %1, %2, %3\n\ts_nop 7\n\ts_nop 7"
               : "=&v"(d) : "v"(a), "v"(b), "v"(c));
  return d;
#endif
}

// --------------------------------------------------------------------------
__global__ void k_prep(const float* __restrict__ Wq, const float* __restrict__ Wk,
                       const float* __restrict__ Wv, const float* __restrict__ Wa1,
                       const float* __restrict__ Wa2, const float* __restrict__ Wa3,
                       const float* __restrict__ Wf, float* __restrict__ P) {
  int tid = threadIdx.x;
  for (int i = tid; i < 1344; i += 256) {        // [conv][co][28]
    int conv = i / 448, r = i % 448, co = r / 28, tap = r % 28;
    const float* W = conv == 0 ? Wq : conv == 1 ? Wk : Wv;
    P[i] = (tap < 27) ? W[co * 27 + tap] : 0.f;
  }
  for (int i = tid; i < 6912; i += 256) {        // Wf[co][ci][27] -> [ci][tap][co]
    int co = i / 432, r = i % 432, ci = r / 27, tap = r % 27;
    P[PW_F + (ci * 27 + tap) * 16 + co] = Wf[i];
  }
}

// --------------------------------------------------------------------------
// k1: tile (z,y,x)=(4,4,64), 1024 voxels, 4 consecutive-x per thread.
__global__ __launch_bounds__(256) void k1_qkv(
    const float* __restrict__ c, const float* __restrict__ e,
    const float* __restrict__ pos, const float* __restrict__ P,
    const float* __restrict__ bq, const float* __restrict__ bk,
    const float* __restrict__ bv, float* __restrict__ q,
    float* __restrict__ k, float* __restrict__ v) {
  __shared__ __align__(16) float se[2448];   // 6*6*68
  __shared__ __align__(16) float sc[2448];
  __shared__ __align__(16) float wl[1344];
  const int t = blockIdx.y;
  const int tile = blockIdx.x;               // 256 = 16z * 16y
  const int y0 = (tile & 15) * 4;
  const int z0 = (tile >> 4) * 4;
  for (int i = threadIdx.x; i < 1344; i += 256) wl[i] = P[i];
  const float* cin = c + t * V18;
  const float* ein = e + t * V18;
  for (int i = threadIdx.x; i < 2448; i += 256) {
    int lz = i / 408, r = i % 408, ly = r / 68, lx = r % 68;
    int gz = z0 + lz - 1, gy = y0 + ly - 1, gx = lx - 1;
    float pe = 0.f, pc = 0.f;
    if (lx < 66 && (unsigned)gz < 64u && (unsigned)gy < 64u && (unsigned)gx < 64u) {
      int gi = (gz << 12) + (gy << 6) + gx;
      float pv = pos[gi];
      pc = cin[gi] + pv;
      pe = ein[gi] + pv;
    }
    se[i] = pe;
    sc[i] = pc;
  }
  __syncthreads();

  const int lz = threadIdx.x >> 6, ly = (threadIdx.x >> 4) & 3,
            lx = (threadIdx.x & 15) * 4;
  const int gi = ((z0 + lz) << 12) + ((y0 + ly) << 6) + lx;

  // ---- pass 1: q (input e) ----
  {
    float xr[3][3][6];
#pragma unroll
    for (int dz = 0; dz < 3; ++dz)
#pragma unroll
      for (int dy = 0; dy < 3; ++dy) {
        int base = ((lz + dz) * 6 + (ly + dy)) * 68 + lx;
        float4 a = *(const float4*)&se[base];
        float2 b2 = *(const float2*)&se[base + 4];
        xr[dz][dy][0] = a.x; xr[dz][dy][1] = a.y; xr[dz][dy][2] = a.z;
        xr[dz][dy][3] = a.w; xr[dz][dy][4] = b2.x; xr[dz][dy][5] = b2.y;
      }
#pragma unroll 1
    for (int co = 0; co < 16; ++co) {
      float bias = bq[co];
      float4 acc = {bias, bias, bias, bias};
      const float* wp = &wl[co * 28];
#pragma unroll
      for (int tg = 0; tg < 7; ++tg) {
        float4 w4 = *(const float4*)&wp[tg * 4];
#pragma unroll
        for (int j = 0; j < 4; ++j) {
          const int tap = tg * 4 + j;
          if (tap < 27) {
            const int dz = tap / 9, dy = (tap / 3) % 3, dx = tap % 3;
            float w = COMP(w4, j);
            acc.x += w * xr[dz][dy][dx + 0];
            acc.y += w * xr[dz][dy][dx + 1];
            acc.z += w * xr[dz][dy][dx + 2];
            acc.w += w * xr[dz][dy][dx + 3];
          }
        }
      }
      *(float4*)&q[((t * 16 + co) << 18) + gi] = acc;
    }
  }
  // ---- pass 2: k, v (input c) ----
  {
    float xr[3][3][6];
#pragma unroll
    for (int dz = 0; dz < 3; ++dz)
#pragma unroll
      for (int dy = 0; dy < 3; ++dy) {
        int base = ((lz + dz) * 6 + (ly + dy)) * 68 + lx;
        float4 a = *(const float4*)&sc[base];
        float2 b2 = *(const float2*)&sc[base + 4];
        xr[dz][dy][0] = a.x; xr[dz][dy][1] = a.y; xr[dz][dy][2] = a.z;
        xr[dz][dy][3] = a.w; xr[dz][dy][4] = b2.x; xr[dz][dy][5] = b2.y;
      }
#pragma unroll 1
    for (int co = 0; co < 16; ++co) {
      float bk_ = bk[co], bv_ = bv[co];
      float4 ak = {bk_, bk_, bk_, bk_};
      float4 av = {bv_, bv_, bv_, bv_};
      const float* wpk = &wl[448 + co * 28];
      const float* wpv = &wl[896 + co * 28];
#pragma unroll
      for (int tg = 0; tg < 7; ++tg) {
        float4 wk4 = *(const float4*)&wpk[tg * 4];
        float4 wv4 = *(const float4*)&wpv[tg * 4];
#pragma unroll
        for (int j = 0; j < 4; ++j) {
          const int tap = tg * 4 + j;
          if (tap < 27) {
            const int dz = tap / 9, dy = (tap / 3) % 3, dx = tap % 3;
            float wk_ = COMP(wk4, j), wv_ = COMP(wv4, j);
            ak.x += wk_ * xr[dz][dy][dx + 0];
            ak.y += wk_ * xr[dz][dy][dx + 1];
            ak.z += wk_ * xr[dz][dy][dx + 2];
            ak.w += wk_ * xr[dz][dy][dx + 3];
            av.x += wv_ * xr[dz][dy][dx + 0];
            av.y += wv_ * xr[dz][dy][dx + 1];
            av.z += wv_ * xr[dz][dy][dx + 2];
            av.w += wv_ * xr[dz][dy][dx + 3];
          }
        }
      }
      *(float4*)&k[((t * 16 + co) << 18) + gi] = ak;
      *(float4*)&v[((t * 16 + co) << 18) + gi] = av;
    }
  }
}

// --------------------------------------------------------------------------
__global__ __launch_bounds__(256) void kstats(const float* __restrict__ src,
                                              float* __restrict__ sums) {
  const int plane = blockIdx.y;
  const float4* s4 = (const float4*)src + (plane << 16) + (blockIdx.x << 13) +
                     threadIdx.x;
  float s = 0.f, s2 = 0.f;
#pragma unroll
  for (int j = 0; j < 32; ++j) {
    float4 val = s4[j * 256];
    s += val.x + val.y + val.z + val.w;
    s2 += val.x * val.x + val.y * val.y + val.z * val.z + val.w * val.w;
  }
#pragma unroll
  for (int d = 32; d > 0; d >>= 1) {
    s += __shfl_xor(s, d);
    s2 += __shfl_xor(s2, d);
  }
  __shared__ float rs[8];
  const int wid = threadIdx.x >> 6;
  if ((threadIdx.x & 63) == 0) {
    rs[wid] = s;
    rs[4 + wid] = s2;
  }
  __syncthreads();
  if (threadIdx.x == 0) {
    atomicAdd(&sums[plane * 2], rs[0] + rs[1] + rs[2] + rs[3]);
    atomicAdd(&sums[plane * 2 + 1], rs[4] + rs[5] + rs[6] + rs[7]);
  }
}

// --------------------------------------------------------------------------
__global__ void k_finstats(const float* __restrict__ sums, float* __restrict__ mr,
                           int n, float invn) {
  int i = blockIdx.x * blockDim.x + threadIdx.x;
  if (i >= n) return;
  float m = sums[i * 2] * invn;
  float var = sums[i * 2 + 1] * invn - m * m;
  mr[i * 2] = m;
  mr[i * 2 + 1] = rsqrtf(fmaxf(var, 0.f) + 1e-5f);
}

// --------------------------------------------------------------------------
// k2: MFMA gating. Wave = 16 voxels; lane holds channel quad c0..c0+3 of
// voxel (lane&15), c0 = (lane>>4)*4. All matmuls via swapped-operand
// mfma_f32_16x16x16_f16; layout is closed under chaining (C row-quad ==
// B-frag k-quad).
__global__ __launch_bounds__(256) void k2_attn(
    const float* __restrict__ q, const float* __restrict__ k,
    const float* __restrict__ v, const float* __restrict__ Wa1,
    const float* __restrict__ Wa2, const float* __restrict__ Wa3,
    const float* __restrict__ mr, const float* __restrict__ ba1,
    const float* __restrict__ ba2, const float* __restrict__ ba3,
    float* __restrict__ u) {
  const int lane = threadIdx.x & 63;
  const int wid = threadIdx.x >> 6;
  const int row = lane & 15;           // voxel-in-group / weight row (o)
  const int c0 = (lane >> 4) * 4;      // channel quad base
  const int vox = (blockIdx.x * 4 + wid) * 16 + row;

  // weight A-frags: element Wa[row=o][k=c0+j], contiguous float4.
  f32x4 w1f = *(const f32x4*)&Wa1[row * 16 + c0];
  f32x4 w2f = *(const f32x4*)&Wa2[row * 16 + c0];
  f32x4 w3f = *(const f32x4*)&Wa3[row * 16 + c0];
  f16x4 wa1 = {(_Float16)w1f[0], (_Float16)w1f[1], (_Float16)w1f[2], (_Float16)w1f[3]};
  f16x4 wa2 = {(_Float16)w2f[0], (_Float16)w2f[1], (_Float16)w2f[2], (_Float16)w2f[3]};
  f16x4 wa3 = {(_Float16)w3f[0], (_Float16)w3f[1], (_Float16)w3f[2], (_Float16)w3f[3]};
  // bias C-inits: lane holds output rows c0..c0+3
  f32x4 b1q = *(const f32x4*)&ba1[c0];
  f32x4 b2q = *(const f32x4*)&ba2[c0];
  f32x4 b3q = *(const f32x4*)&ba3[c0];

  f32x4 A[8], acc[8];
  f16x4 qn[8];
#pragma unroll
  for (int t = 0; t < 8; ++t) {
    f32x4 s01 = *(const f32x4*)&mr[(t * 16 + c0) * 2];
    f32x4 s23 = *(const f32x4*)&mr[(t * 16 + c0) * 2 + 4];
    float x0 = lrelu((q[((t * 16 + c0 + 0) << 18) + vox] - s01[0]) * s01[1]);
    float x1 = lrelu((q[((t * 16 + c0 + 1) << 18) + vox] - s01[2]) * s01[3]);
    float x2 = lrelu((q[((t * 16 + c0 + 2) << 18) + vox] - s23[0]) * s23[1]);
    float x3 = lrelu((q[((t * 16 + c0 + 3) << 18) + vox] - s23[2]) * s23[3]);
    qn[t] = (f16x4){(_Float16)x0, (_Float16)x1, (_Float16)x2, (_Float16)x3};
    A[t] = mfma16(wa1, qn[t], b1q);
    acc[t] = (f32x4){0.f, 0.f, 0.f, 0.f};
  }
#pragma unroll 1
  for (int j = 0; j < 8; ++j) {
    f32x4 sk01 = *(const f32x4*)&mr[256 + (j * 16 + c0) * 2];
    f32x4 sk23 = *(const f32x4*)&mr[256 + (j * 16 + c0) * 2 + 4];
    f32x4 sv01 = *(const f32x4*)&mr[512 + (j * 16 + c0) * 2];
    f32x4 sv23 = *(const f32x4*)&mr[512 + (j * 16 + c0) * 2 + 4];
    float k0 = lrelu((k[((j * 16 + c0 + 0) << 18) + vox] - sk01[0]) * sk01[1]);
    float k1 = lrelu((k[((j * 16 + c0 + 1) << 18) + vox] - sk01[2]) * sk01[3]);
    float k2 = lrelu((k[((j * 16 + c0 + 2) << 18) + vox] - sk23[0]) * sk23[1]);
    float k3 = lrelu((k[((j * 16 + c0 + 3) << 18) + vox] - sk23[2]) * sk23[3]);
    f32x4 vnq;
    vnq[0] = lrelu((v[((j * 16 + c0 + 0) << 18) + vox] - sv01[0]) * sv01[1]);
    vnq[1] = lrelu((v[((j * 16 + c0 + 1) << 18) + vox] - sv01[2]) * sv01[3]);
    vnq[2] = lrelu((v[((j * 16 + c0 + 2) << 18) + vox] - sv23[0]) * sv23[1]);
    vnq[3] = lrelu((v[((j * 16 + c0 + 3) << 18) + vox] - sv23[2]) * sv23[3]);
    f16x4 knh = (f16x4){(_Float16)k0, (_Float16)k1, (_Float16)k2, (_Float16)k3};
    f32x4 B = mfma16(wa2, knh, b2q);
#pragma unroll
    for (int i = 0; i < 8; ++i) {
      f32x4 rel = A[i] + B;
      f16x4 rh = (f16x4){(_Float16)fmaxf(rel[0], 0.f), (_Float16)fmaxf(rel[1], 0.f),
                         (_Float16)fmaxf(rel[2], 0.f), (_Float16)fmaxf(rel[3], 0.f)};
      f32x4 s = mfma16(wa3, rh, b3q);
      acc[i][0] += sigm(s[0]) * vnq[0];
      acc[i][1] += sigm(s[1]) * vnq[1];
      acc[i][2] += sigm(s[2]) * vnq[2];
      acc[i][3] += sigm(s[3]) * vnq[3];
    }
  }
#pragma unroll
  for (int t = 0; t < 8; ++t) {
    u[((t * 16 + c0 + 0) << 18) + vox] = acc[t][0] + (float)qn[t][0];
    u[((t * 16 + c0 + 1) << 18) + vox] = acc[t][1] + (float)qn[t][1];
    u[((t * 16 + c0 + 2) << 18) + vox] = acc[t][2] + (float)qn[t][2];
    u[((t * 16 + c0 + 3) << 18) + vox] = acc[t][3] + (float)qn[t][3];
  }
}

// --------------------------------------------------------------------------
// k3: tile (z,y,x)=(2,8,64), 1024 voxels, 4 consecutive-x per thread.
__global__ __launch_bounds__(256) void k3_conv(
    const float* __restrict__ u, const float* __restrict__ P,
    const float* __restrict__ bfv, float* __restrict__ y) {
  __shared__ __align__(16) float sx[4 * 2720];  // 4 ci * (4*10*68)
  __shared__ __align__(16) float wf[1728];      // 4 ci * 27 tap * 16 co
  const int t = blockIdx.y;
  const int tile = blockIdx.x;                  // 256 = 32z * 8y
  const int y0 = (tile & 7) * 8;
  const int z0 = (tile >> 3) * 2;
  const int lz = threadIdx.x >> 7, ly = (threadIdx.x >> 4) & 7,
            lx = (threadIdx.x & 15) * 4;
  const int gi = ((z0 + lz) << 12) + ((y0 + ly) << 6) + lx;

  float acc[16][4];
#pragma unroll
  for (int co = 0; co < 16; ++co) {
    float b = bfv[co];
    acc[co][0] = b; acc[co][1] = b; acc[co][2] = b; acc[co][3] = b;
  }

#pragma unroll 1
  for (int cig = 0; cig < 4; ++cig) {
    __syncthreads();
    for (int i = threadIdx.x; i < 4 * 2720; i += 256) {
      int ci_l = i / 2720, r = i % 2720;
      int lzz = r / 680, r2 = r % 680, lyy = r2 / 68, lxx = r2 % 68;
      int gz = z0 + lzz - 1, gy = y0 + lyy - 1, gx = lxx - 1;
      float val = 0.f;
      if (lxx < 66 && (unsigned)gz < 64u && (unsigned)gy < 64u && (unsigned)gx < 64u)
        val = u[((t * 16 + cig * 4 + ci_l) << 18) + (gz << 12) + (gy << 6) + gx];
      sx[i] = val;
    }
    for (int i = threadIdx.x; i < 1728; i += 256)
      wf[i] = P[PW_F + cig * 1728 + i];
    __syncthreads();

#pragma unroll 1
    for (int ci_l = 0; ci_l < 4; ++ci_l) {
      float xr[3][3][6];
      const float* sp = sx + ci_l * 2720;
#pragma unroll
      for (int dz = 0; dz < 3; ++dz)
#pragma unroll
        for (int dy = 0; dy < 3; ++dy) {
          int base = ((lz + dz) * 10 + (ly + dy)) * 68 + lx;
          float4 a = *(const float4*)&sp[base];
          float2 b2 = *(const float2*)&sp[base + 4];
          xr[dz][dy][0] = a.x; xr[dz][dy][1] = a.y; xr[dz][dy][2] = a.z;
          xr[dz][dy][3] = a.w; xr[dz][dy][4] = b2.x; xr[dz][dy][5] = b2.y;
        }
      const float* wbase = &wf[ci_l * 432];
#pragma unroll
      for (int tap = 0; tap < 27; ++tap) {
        const int dz = tap / 9, dy = (tap / 3) % 3, dx = tap % 3;
        float4 w0 = *(const float4*)&wbase[tap * 16 + 0];
        float4 w1 = *(const float4*)&wbase[tap * 16 + 4];
        float4 w2 = *(const float4*)&wbase[tap * 16 + 8];
        float4 w3 = *(const float4*)&wbase[tap * 16 + 12];
        float xv0 = xr[dz][dy][dx + 0], xv1 = xr[dz][dy][dx + 1];
        float xv2 = xr[dz][dy][dx + 2], xv3 = xr[dz][dy][dx + 3];
#pragma unroll
        for (int co = 0; co < 16; ++co) {
          float w = COMP((co < 4 ? w0 : co < 8 ? w1 : co < 12 ? w2 : w3), co & 3);
          acc[co][0] += w * xv0;
          acc[co][1] += w * xv1;
          acc[co][2] += w * xv2;
          acc[co][3] += w * xv3;
        }
      }
    }
  }
#pragma unroll
  for (int co = 0; co < 16; ++co) {
    float4 o = {acc[co][0], acc[co][1], acc[co][2], acc[co][3]};
    *(float4*)&y[((t * 16 + co) << 18) + gi] = o;
  }
}

// --------------------------------------------------------------------------
__global__ __launch_bounds__(256) void k4_norm(const float* __restrict__ y,
                                               const float* __restrict__ fmr,
                                               float* __restrict__ out) {
  int tid = blockIdx.x * 256 + threadIdx.x;
#pragma unroll 1
  for (int it = 0; it < 8; ++it) {
    int i4 = tid + it * 1048576;
    int plane = (i4 << 2) >> 18;
    float m = fmr[plane * 2], rs = fmr[plane * 2 + 1];
    float4 val = reinterpret_cast<const float4*>(y)[i4];
    float4 o;
    o.x = lrelu((val.x - m) * rs);
    o.y = lrelu((val.y - m) * rs);
    o.z = lrelu((val.z - m) * rs);
    o.w = lrelu((val.w - m) * rs);
    reinterpret_cast<float4*>(out)[i4] = o;
  }
}

// --------------------------------------------------------------------------
extern "C" void kernel_launch(void* const* d_in, const int* in_sizes, int n_in,
                              void* d_out, int out_size, void* d_ws, size_t ws_size,
                              hipStream_t stream) {
  const float* c = (const float*)d_in[0];
  const float* e = (const float*)d_in[1];
  const float* pos = (const float*)d_in[2];
  const float* Wq = (const float*)d_in[3];
  const float* bq = (const float*)d_in[4];
  const float* Wk = (const float*)d_in[5];
  const float* bk = (const float*)d_in[6];
  const float* Wv = (const float*)d_in[7];
  const float* bv = (const float*)d_in[8];
  const float* Wa1 = (const float*)d_in[9];
  const float* ba1 = (const float*)d_in[10];
  const float* Wa2 = (const float*)d_in[11];
  const float* ba2 = (const float*)d_in[12];
  const float* Wa3 = (const float*)d_in[13];
  const float* ba3 = (const float*)d_in[14];
  const float* Wf = (const float*)d_in[15];
  const float* bf_ = (const float*)d_in[16];

  float* ws = (float*)d_ws;
  float* q = ws;
  float* k = ws + QKV_FLOATS;
  float* v = ws + 2 * QKV_FLOATS;
  float* y = ws;                   // aliases q (dead after k2)
  float* stats = ws + SOFF;        // qkv sums: 768
  float* fsums = stats + 768;      // 256
  float* qkvmr = stats + 1024;     // 768
  float* fmr = stats + 1792;       // 256
  float* P = stats + 2048;         // packed weights
  float* uo = (float*)d_out;

  hipMemsetAsync(stats, 0, 1024 * sizeof(float), stream);
  hipLaunchKernelGGL(k_prep, dim3(1), dim3(256), 0, stream,
                     Wq, Wk, Wv, Wa1, Wa2, Wa3, Wf, P);
  hipLaunchKernelGGL(k1_qkv, dim3(256, 8), dim3(256), 0, stream,
                     c, e, pos, P, bq, bk, bv, q, k, v);
  hipLaunchKernelGGL(kstats, dim3(8, 384), dim3(256), 0, stream, q, stats);
  hipLaunchKernelGGL(k_finstats, dim3(2), dim3(256), 0, stream,
                     stats, qkvmr, 384, 1.f / 262144.f);
  hipLaunchKernelGGL(k2_attn, dim3(4096), dim3(256), 0, stream,
                     q, k, v, Wa1, Wa2, Wa3, qkvmr, ba1, ba2, ba3, uo);
  hipLaunchKernelGGL(k3_conv, dim3(256, 8), dim3(256), 0, stream,
                     uo, P, bf_, y);
  hipLaunchKernelGGL(kstats, dim3(8, 128), dim3(256), 0, stream, y, fsums);
  hipLaunchKernelGGL(k_finstats, dim3(1), dim3(256), 0, stream,
                     fsums, fmr, 128, 1.f / 262144.f);
  hipLaunchKernelGGL(k4_norm, dim3(4096), dim3(256), 0, stream, y, fmr, uo);
}

// Round 4
// 504.059 us; speedup vs baseline: 5.5250x; 1.7246x over previous
//
#include <hip/hip_runtime.h>
#include <hip/hip_bf16.h>
#include <math.h>

// ---------------------------------------------------------------------------
// ConvFormer: T=8, Ci=1, Co=16, spatial 64^3.
//   k_prep:  repack k1 conv weights (fp32) + k3 MFMA weight frags (f16)
//   k1_qkv:  q/k/v 3x3x3 convs (fp32, weights in LDS, 4 vox/thread)
//   kstats:  per-plane sum/sumsq on fp32 q/k/v -> k_finstats: mean/rstd
//   k2_attn: MFMA gating (verified swapped-operand mfma_f32_16x16x16_f16
//            convention: A-frag lane l = W[row=l&15][k=(l>>4)*4+j],
//            B-frag lane l = X[k=(l>>4)*4+j][col=l&15],
//            C lane l = C[row=(l>>4)*4+j][col=l&15]).
//            Writes u as f16 [vox][ci] interleaved into d_out.
//   k3_conv: final 16->16 conv as implicit GEMM on MFMA. LDS tile
//            [z4][y6][x66][ci16] f16; B-frag = one ds_read_b64; 27 taps
//            x 8 vox-groups per wave. Fused instance-norm stats.
//            Writes y f16 [vox][ci] into ws.
//   k_finstats on fsums;  k4_norm: interleaved y -> planar fp32 d_out
// ---------------------------------------------------------------------------

#define V18 (1 << 18)
#define QKV_FLOATS (1 << 25)
#define SOFF (3 * QKV_FLOATS)

#define COMP(v, j) ((j) == 0 ? (v).x : (j) == 1 ? (v).y : (j) == 2 ? (v).z : (v).w)

typedef __attribute__((ext_vector_type(4))) _Float16 f16x4;
typedef __attribute__((ext_vector_type(8))) _Float16 f16x8;
typedef __attribute__((ext_vector_type(4))) float f32x4;

__device__ __forceinline__ float lrelu(float x) { return x > 0.f ? x : 0.2f * x; }
__device__ __forceinline__ float sigm(float x) {
  return __builtin_amdgcn_rcpf(1.f + __expf(-x));
}

__device__ __forceinline__ f32x4 mfma16(f16x4 a, f16x4 b, f32x4 c) {
  return __builtin_amdgcn_mfma_f32_16x16x16f16(a, b, c, 0, 0, 0);
}

// --------------------------------------------------------------------------
__global__ void k_prep(const float* __restrict__ Wq, const float* __restrict__ Wk,
                       const float* __restrict__ Wv, const float* __restrict__ Wf,
                       float* __restrict__ P) {
  int tid = threadIdx.x;
  for (int i = tid; i < 1344; i += 256) {        // [conv][co][28]
    int conv = i / 448, r = i % 448, co = r / 28, tap = r % 28;
    const float* W = conv == 0 ? Wq : conv == 1 ? Wk : Wv;
    P[i] = (tap < 27) ? W[co * 27 + tap] : 0.f;
  }
  // k3 MFMA A-frags: wf16[tap][lane][j] = Wf[co=lane&15][ci=(lane>>4)*4+j][tap]
  _Float16* wf16 = (_Float16*)(P + 1344);
  for (int i = tid; i < 6912; i += 256) {
    int tap = i >> 8, r = i & 255, lane = r >> 2, j = r & 3;
    wf16[i] = (_Float16)Wf[(lane & 15) * 432 + ((lane >> 4) * 4 + j) * 27 + tap];
  }
}

// --------------------------------------------------------------------------
// k1: tile (z,y,x)=(4,4,64), 1024 voxels, 4 consecutive-x per thread.
__global__ __launch_bounds__(256) void k1_qkv(
    const float* __restrict__ c, const float* __restrict__ e,
    const float* __restrict__ pos, const float* __restrict__ P,
    const float* __restrict__ bq, const float* __restrict__ bk,
    const float* __restrict__ bv, float* __restrict__ q,
    float* __restrict__ k, float* __restrict__ v) {
  __shared__ __align__(16) float se[2448];   // 6*6*68
  __shared__ __align__(16) float sc[2448];
  __shared__ __align__(16) float wl[1344];
  const int t = blockIdx.y;
  const int tile = blockIdx.x;               // 256 = 16z * 16y
  const int y0 = (tile & 15) * 4;
  const int z0 = (tile >> 4) * 4;
  for (int i = threadIdx.x; i < 1344; i += 256) wl[i] = P[i];
  const float* cin = c + t * V18;
  const float* ein = e + t * V18;
  for (int i = threadIdx.x; i < 2448; i += 256) {
    int lz = i / 408, r = i % 408, ly = r / 68, lx = r % 68;
    int gz = z0 + lz - 1, gy = y0 + ly - 1, gx = lx - 1;
    float pe = 0.f, pc = 0.f;
    if (lx < 66 && (unsigned)gz < 64u && (unsigned)gy < 64u && (unsigned)gx < 64u) {
      int gi = (gz << 12) + (gy << 6) + gx;
      float pv = pos[gi];
      pc = cin[gi] + pv;
      pe = ein[gi] + pv;
    }
    se[i] = pe;
    sc[i] = pc;
  }
  __syncthreads();

  const int lz = threadIdx.x >> 6, ly = (threadIdx.x >> 4) & 3,
            lx = (threadIdx.x & 15) * 4;
  const int gi = ((z0 + lz) << 12) + ((y0 + ly) << 6) + lx;

  // ---- pass 1: q (input e) ----
  {
    float xr[3][3][6];
#pragma unroll
    for (int dz = 0; dz < 3; ++dz)
#pragma unroll
      for (int dy = 0; dy < 3; ++dy) {
        int base = ((lz + dz) * 6 + (ly + dy)) * 68 + lx;
        float4 a = *(const float4*)&se[base];
        float2 b2 = *(const float2*)&se[base + 4];
        xr[dz][dy][0] = a.x; xr[dz][dy][1] = a.y; xr[dz][dy][2] = a.z;
        xr[dz][dy][3] = a.w; xr[dz][dy][4] = b2.x; xr[dz][dy][5] = b2.y;
      }
#pragma unroll 1
    for (int co = 0; co < 16; ++co) {
      float bias = bq[co];
      float4 acc = {bias, bias, bias, bias};
      const float* wp = &wl[co * 28];
#pragma unroll
      for (int tg = 0; tg < 7; ++tg) {
        float4 w4 = *(const float4*)&wp[tg * 4];
#pragma unroll
        for (int j = 0; j < 4; ++j) {
          const int tap = tg * 4 + j;
          if (tap < 27) {
            const int dz = tap / 9, dy = (tap / 3) % 3, dx = tap % 3;
            float w = COMP(w4, j);
            acc.x += w * xr[dz][dy][dx + 0];
            acc.y += w * xr[dz][dy][dx + 1];
            acc.z += w * xr[dz][dy][dx + 2];
            acc.w += w * xr[dz][dy][dx + 3];
          }
        }
      }
      *(float4*)&q[((t * 16 + co) << 18) + gi] = acc;
    }
  }
  // ---- pass 2: k, v (input c) ----
  {
    float xr[3][3][6];
#pragma unroll
    for (int dz = 0; dz < 3; ++dz)
#pragma unroll
      for (int dy = 0; dy < 3; ++dy) {
        int base = ((lz + dz) * 6 + (ly + dy)) * 68 + lx;
        float4 a = *(const float4*)&sc[base];
        float2 b2 = *(const float2*)&sc[base + 4];
        xr[dz][dy][0] = a.x; xr[dz][dy][1] = a.y; xr[dz][dy][2] = a.z;
        xr[dz][dy][3] = a.w; xr[dz][dy][4] = b2.x; xr[dz][dy][5] = b2.y;
      }
#pragma unroll 1
    for (int co = 0; co < 16; ++co) {
      float bk_ = bk[co], bv_ = bv[co];
      float4 ak = {bk_, bk_, bk_, bk_};
      float4 av = {bv_, bv_, bv_, bv_};
      const float* wpk = &wl[448 + co * 28];
      const float* wpv = &wl[896 + co * 28];
#pragma unroll
      for (int tg = 0; tg < 7; ++tg) {
        float4 wk4 = *(const float4*)&wpk[tg * 4];
        float4 wv4 = *(const float4*)&wpv[tg * 4];
#pragma unroll
        for (int j = 0; j < 4; ++j) {
          const int tap = tg * 4 + j;
          if (tap < 27) {
            const int dz = tap / 9, dy = (tap / 3) % 3, dx = tap % 3;
            float wk_ = COMP(wk4, j), wv_ = COMP(wv4, j);
            ak.x += wk_ * xr[dz][dy][dx + 0];
            ak.y += wk_ * xr[dz][dy][dx + 1];
            ak.z += wk_ * xr[dz][dy][dx + 2];
            ak.w += wk_ * xr[dz][dy][dx + 3];
            av.x += wv_ * xr[dz][dy][dx + 0];
            av.y += wv_ * xr[dz][dy][dx + 1];
            av.z += wv_ * xr[dz][dy][dx + 2];
            av.w += wv_ * xr[dz][dy][dx + 3];
          }
        }
      }
      *(float4*)&k[((t * 16 + co) << 18) + gi] = ak;
      *(float4*)&v[((t * 16 + co) << 18) + gi] = av;
    }
  }
}

// --------------------------------------------------------------------------
__global__ __launch_bounds__(256) void kstats(const float* __restrict__ src,
                                              float* __restrict__ sums) {
  const int plane = blockIdx.y;
  const float4* s4 = (const float4*)src + (plane << 16) + (blockIdx.x << 13) +
                     threadIdx.x;
  float s = 0.f, s2 = 0.f;
#pragma unroll
  for (int j = 0; j < 32; ++j) {
    float4 val = s4[j * 256];
    s += val.x + val.y + val.z + val.w;
    s2 += val.x * val.x + val.y * val.y + val.z * val.z + val.w * val.w;
  }
#pragma unroll
  for (int d = 32; d > 0; d >>= 1) {
    s += __shfl_xor(s, d);
    s2 += __shfl_xor(s2, d);
  }
  __shared__ float rs[8];
  const int wid = threadIdx.x >> 6;
  if ((threadIdx.x & 63) == 0) {
    rs[wid] = s;
    rs[4 + wid] = s2;
  }
  __syncthreads();
  if (threadIdx.x == 0) {
    atomicAdd(&sums[plane * 2], rs[0] + rs[1] + rs[2] + rs[3]);
    atomicAdd(&sums[plane * 2 + 1], rs[4] + rs[5] + rs[6] + rs[7]);
  }
}

// --------------------------------------------------------------------------
__global__ void k_finstats(const float* __restrict__ sums, float* __restrict__ mr,
                           int n, float invn) {
  int i = blockIdx.x * blockDim.x + threadIdx.x;
  if (i >= n) return;
  float m = sums[i * 2] * invn;
  float var = sums[i * 2 + 1] * invn - m * m;
  mr[i * 2] = m;
  mr[i * 2 + 1] = rsqrtf(fmaxf(var, 0.f) + 1e-5f);
}

// --------------------------------------------------------------------------
// k2: MFMA gating; writes u f16 interleaved [vox][ci].
__global__ __launch_bounds__(256) void k2_attn(
    const float* __restrict__ q, const float* __restrict__ k,
    const float* __restrict__ v, const float* __restrict__ Wa1,
    const float* __restrict__ Wa2, const float* __restrict__ Wa3,
    const float* __restrict__ mr, const float* __restrict__ ba1,
    const float* __restrict__ ba2, const float* __restrict__ ba3,
    _Float16* __restrict__ u) {
  const int lane = threadIdx.x & 63;
  const int wid = threadIdx.x >> 6;
  const int row = lane & 15;           // voxel-in-group / weight row (o)
  const int c0 = (lane >> 4) * 4;      // channel quad base
  const int vox = (blockIdx.x * 4 + wid) * 16 + row;

  f32x4 w1f = *(const f32x4*)&Wa1[row * 16 + c0];
  f32x4 w2f = *(const f32x4*)&Wa2[row * 16 + c0];
  f32x4 w3f = *(const f32x4*)&Wa3[row * 16 + c0];
  f16x4 wa1 = {(_Float16)w1f[0], (_Float16)w1f[1], (_Float16)w1f[2], (_Float16)w1f[3]};
  f16x4 wa2 = {(_Float16)w2f[0], (_Float16)w2f[1], (_Float16)w2f[2], (_Float16)w2f[3]};
  f16x4 wa3 = {(_Float16)w3f[0], (_Float16)w3f[1], (_Float16)w3f[2], (_Float16)w3f[3]};
  f32x4 b1q = *(const f32x4*)&ba1[c0];
  f32x4 b2q = *(const f32x4*)&ba2[c0];
  f32x4 b3q = *(const f32x4*)&ba3[c0];

  f32x4 A[8], acc[8];
  f16x4 qn[8];
#pragma unroll
  for (int t = 0; t < 8; ++t) {
    f32x4 s01 = *(const f32x4*)&mr[(t * 16 + c0) * 2];
    f32x4 s23 = *(const f32x4*)&mr[(t * 16 + c0) * 2 + 4];
    float x0 = lrelu((q[((t * 16 + c0 + 0) << 18) + vox] - s01[0]) * s01[1]);
    float x1 = lrelu((q[((t * 16 + c0 + 1) << 18) + vox] - s01[2]) * s01[3]);
    float x2 = lrelu((q[((t * 16 + c0 + 2) << 18) + vox] - s23[0]) * s23[1]);
    float x3 = lrelu((q[((t * 16 + c0 + 3) << 18) + vox] - s23[2]) * s23[3]);
    qn[t] = (f16x4){(_Float16)x0, (_Float16)x1, (_Float16)x2, (_Float16)x3};
    A[t] = mfma16(wa1, qn[t], b1q);
    acc[t] = (f32x4){0.f, 0.f, 0.f, 0.f};
  }
#pragma unroll 1
  for (int j = 0; j < 8; ++j) {
    f32x4 sk01 = *(const f32x4*)&mr[256 + (j * 16 + c0) * 2];
    f32x4 sk23 = *(const f32x4*)&mr[256 + (j * 16 + c0) * 2 + 4];
    f32x4 sv01 = *(const f32x4*)&mr[512 + (j * 16 + c0) * 2];
    f32x4 sv23 = *(const f32x4*)&mr[512 + (j * 16 + c0) * 2 + 4];
    float k0 = lrelu((k[((j * 16 + c0 + 0) << 18) + vox] - sk01[0]) * sk01[1]);
    float k1 = lrelu((k[((j * 16 + c0 + 1) << 18) + vox] - sk01[2]) * sk01[3]);
    float k2 = lrelu((k[((j * 16 + c0 + 2) << 18) + vox] - sk23[0]) * sk23[1]);
    float k3 = lrelu((k[((j * 16 + c0 + 3) << 18) + vox] - sk23[2]) * sk23[3]);
    f32x4 vnq;
    vnq[0] = lrelu((v[((j * 16 + c0 + 0) << 18) + vox] - sv01[0]) * sv01[1]);
    vnq[1] = lrelu((v[((j * 16 + c0 + 1) << 18) + vox] - sv01[2]) * sv01[3]);
    vnq[2] = lrelu((v[((j * 16 + c0 + 2) << 18) + vox] - sv23[0]) * sv23[1]);
    vnq[3] = lrelu((v[((j * 16 + c0 + 3) << 18) + vox] - sv23[2]) * sv23[3]);
    f16x4 knh = (f16x4){(_Float16)k0, (_Float16)k1, (_Float16)k2, (_Float16)k3};
    f32x4 B = mfma16(wa2, knh, b2q);
#pragma unroll
    for (int i = 0; i < 8; ++i) {
      f32x4 rel = A[i] + B;
      f16x4 rh = (f16x4){(_Float16)fmaxf(rel[0], 0.f), (_Float16)fmaxf(rel[1], 0.f),
                         (_Float16)fmaxf(rel[2], 0.f), (_Float16)fmaxf(rel[3], 0.f)};
      f32x4 s = mfma16(wa3, rh, b3q);
      acc[i][0] += sigm(s[0]) * vnq[0];
      acc[i][1] += sigm(s[1]) * vnq[1];
      acc[i][2] += sigm(s[2]) * vnq[2];
      acc[i][3] += sigm(s[3]) * vnq[3];
    }
  }
#pragma unroll
  for (int t = 0; t < 8; ++t) {
    f16x4 o = {(_Float16)(acc[t][0] + (float)qn[t][0]),
               (_Float16)(acc[t][1] + (float)qn[t][1]),
               (_Float16)(acc[t][2] + (float)qn[t][2]),
               (_Float16)(acc[t][3] + (float)qn[t][3])};
    *(f16x4*)&u[((size_t)t << 22) + (vox << 4) + c0] = o;
  }
}

// --------------------------------------------------------------------------
// k3: implicit-GEMM MFMA conv. Tile (z,y,x)=(2,4,64)=512 vox, 4 waves,
// each wave 128 vox = 8 groups of 16-consecutive-x. LDS [z4][y6][x66][ci16]
// f16. Per (tap, group): one ds_read_b64 B-frag + one mfma. Fused stats.
__global__ __launch_bounds__(256) void k3_conv(
    const _Float16* __restrict__ u16, const _Float16* __restrict__ wf16,
    const float* __restrict__ bfv, _Float16* __restrict__ y16,
    float* __restrict__ fsums) {
  __shared__ __align__(16) _Float16 sx[4 * 6 * 66 * 16];  // 50688 B
  __shared__ float red[32];
  const int t = blockIdx.y;
  const int tile = blockIdx.x;      // 512 = 32z * 16y
  const int y0 = (tile & 15) * 4;
  const int z0 = (tile >> 4) * 2;
  const int tid = threadIdx.x;
  const int lane = tid & 63, wv = tid >> 6;

  if (tid < 32) red[tid] = 0.f;

  // stage u tile (f16 interleaved, halo z/y/x +-1, zeros at boundaries)
  const _Float16* ubase = u16 + ((size_t)t << 22);
  for (int i = tid; i < 3168; i += 256) {
    int row = i / 132, cc = i % 132;          // row = lz*6+ly
    int xs = cc >> 1, ci0 = (cc & 1) * 8;
    int gz = z0 + row / 6 - 1, gy = y0 + row % 6 - 1, gx = xs - 1;
    float4 val = {0.f, 0.f, 0.f, 0.f};
    if ((unsigned)gz < 64u && (unsigned)gy < 64u && (unsigned)gx < 64u)
      val = *(const float4*)&ubase[(((gz << 12) + (gy << 6) + gx) << 4) + ci0];
    *(float4*)&sx[(row * 66 + xs) * 16 + ci0] = val;
  }

  // weight A-frags (27 taps x f16x4) + bias C-init
  f16x4 w[27];
#pragma unroll
  for (int tap = 0; tap < 27; ++tap)
    w[tap] = *(const f16x4*)&wf16[tap * 256 + lane * 4];
  f32x4 bq = *(const f32x4*)&bfv[(lane >> 4) * 4];

  __syncthreads();

  const int zw = wv >> 1;           // wave z: 0..1
  const int ywb = (wv & 1) * 2;     // wave y base: 0 or 2
  f32x4 acc[8];
#pragma unroll
  for (int g = 0; g < 8; ++g) acc[g] = bq;

#pragma unroll
  for (int dz = 0; dz < 3; ++dz)
#pragma unroll
    for (int dy = 0; dy < 3; ++dy)
#pragma unroll
      for (int dx = 0; dx < 3; ++dx) {
        const int tap = (dz * 3 + dy) * 3 + dx;
#pragma unroll
        for (int g = 0; g < 8; ++g) {
          const int ly = ywb + (g >> 2);
          const int row = (zw + dz) * 6 + (ly + dy);
          f16x4 b = *(const f16x4*)
              &sx[(row * 66 + (g & 3) * 16 + (lane & 15) + dx) * 16 + (lane >> 4) * 4];
          acc[g] = mfma16(w[tap], b, acc[g]);
        }
      }

  // store y (f16 interleaved) + fused stats
  float s[4] = {0.f, 0.f, 0.f, 0.f}, s2[4] = {0.f, 0.f, 0.f, 0.f};
  _Float16* ybase = y16 + ((size_t)t << 22);
#pragma unroll
  for (int g = 0; g < 8; ++g) {
    const int ly = ywb + (g >> 2);
    const int gvox = ((z0 + zw) << 12) + ((y0 + ly) << 6) + (g & 3) * 16 + (lane & 15);
    f16x4 o = {(_Float16)acc[g][0], (_Float16)acc[g][1],
               (_Float16)acc[g][2], (_Float16)acc[g][3]};
    *(f16x4*)&ybase[(gvox << 4) + (lane >> 4) * 4] = o;
#pragma unroll
    for (int j = 0; j < 4; ++j) {
      s[j] += acc[g][j];
      s2[j] += acc[g][j] * acc[g][j];
    }
  }
#pragma unroll
  for (int d = 1; d < 16; d <<= 1)
#pragma unroll
    for (int j = 0; j < 4; ++j) {
      s[j] += __shfl_xor(s[j], d);
      s2[j] += __shfl_xor(s2[j], d);
    }
  if ((lane & 15) == 0) {
    const int co0 = (lane >> 4) * 4;
#pragma unroll
    for (int j = 0; j < 4; ++j) {
      atomicAdd(&red[(co0 + j) * 2], s[j]);
      atomicAdd(&red[(co0 + j) * 2 + 1], s2[j]);
    }
  }
  __syncthreads();
  if (tid < 32) atomicAdd(&fsums[t * 32 + tid], red[tid]);
}

// --------------------------------------------------------------------------
// k4: interleaved f16 y -> normalized planar fp32 out.
__global__ __launch_bounds__(256) void k4_norm(const _Float16* __restrict__ y16,
                                               const float* __restrict__ fmr,
                                               float* __restrict__ out) {
  const int t = blockIdx.x >> 8;            // 256 blocks per t
  const int vb = (blockIdx.x & 255) << 10;
  const _Float16* yb = y16 + ((size_t)t << 22);
  float* ob = out + ((size_t)t << 22);
  const float* f = fmr + t * 32;
#pragma unroll 1
  for (int it = 0; it < 4; ++it) {
    const int voxl = vb + it * 256 + threadIdx.x;
    f16x8 h0 = *(const f16x8*)&yb[voxl << 4];
    f16x8 h1 = *(const f16x8*)&yb[(voxl << 4) + 8];
#pragma unroll
    for (int co = 0; co < 8; ++co)
      ob[(co << 18) + voxl] = lrelu(((float)h0[co] - f[co * 2]) * f[co * 2 + 1]);
#pragma unroll
    for (int co = 0; co < 8; ++co)
      ob[((co + 8) << 18) + voxl] =
          lrelu(((float)h1[co] - f[(co + 8) * 2]) * f[(co + 8) * 2 + 1]);
  }
}

// --------------------------------------------------------------------------
extern "C" void kernel_launch(void* const* d_in, const int* in_sizes, int n_in,
                              void* d_out, int out_size, void* d_ws, size_t ws_size,
                              hipStream_t stream) {
  const float* c = (const float*)d_in[0];
  const float* e = (const float*)d_in[1];
  const float* pos = (const float*)d_in[2];
  const float* Wq = (const float*)d_in[3];
  const float* bq = (const float*)d_in[4];
  const float* Wk = (const float*)d_in[5];
  const float* bk = (const float*)d_in[6];
  const float* Wv = (const float*)d_in[7];
  const float* bv = (const float*)d_in[8];
  const float* Wa1 = (const float*)d_in[9];
  const float* ba1 = (const float*)d_in[10];
  const float* Wa2 = (const float*)d_in[11];
  const float* ba2 = (const float*)d_in[12];
  const float* Wa3 = (const float*)d_in[13];
  const float* ba3 = (const float*)d_in[14];
  const float* Wf = (const float*)d_in[15];
  const float* bf_ = (const float*)d_in[16];

  float* ws = (float*)d_ws;
  float* q = ws;
  float* k = ws + QKV_FLOATS;
  float* v = ws + 2 * QKV_FLOATS;
  _Float16* y16 = (_Float16*)ws;   // aliases q (dead after k2)
  float* stats = ws + SOFF;        // qkv sums: 768
  float* fsums = stats + 768;      // 256 (zeroed by memset below)
  float* qkvmr = stats + 1024;     // 768
  float* fmr = stats + 1792;       // 256
  float* P = stats + 2048;         // k1 weights [0,1344) + wf16 frags
  _Float16* wf16 = (_Float16*)(P + 1344);
  _Float16* u16 = (_Float16*)d_out;

  hipMemsetAsync(stats, 0, 1024 * sizeof(float), stream);
  hipLaunchKernelGGL(k_prep, dim3(1), dim3(256), 0, stream, Wq, Wk, Wv, Wf, P);
  hipLaunchKernelGGL(k1_qkv, dim3(256, 8), dim3(256), 0, stream,
                     c, e, pos, P, bq, bk, bv, q, k, v);
  hipLaunchKernelGGL(kstats, dim3(8, 384), dim3(256), 0, stream, q, stats);
  hipLaunchKernelGGL(k_finstats, dim3(2), dim3(256), 0, stream,
                     stats, qkvmr, 384, 1.f / 262144.f);
  hipLaunchKernelGGL(k2_attn, dim3(4096), dim3(256), 0, stream,
                     q, k, v, Wa1, Wa2, Wa3, qkvmr, ba1, ba2, ba3, u16);
  hipLaunchKernelGGL(k3_conv, dim3(512, 8), dim3(256), 0, stream,
                     u16, wf16, bf_, y16, fsums);
  hipLaunchKernelGGL(k_finstats, dim3(1), dim3(256), 0, stream,
                     fsums, fmr, 128, 1.f / 262144.f);
  hipLaunchKernelGGL(k4_norm, dim3(2048), dim3(256), 0, stream, y16, fmr,
                     (float*)d_out);
}

// Round 5
// 375.102 us; speedup vs baseline: 7.4244x; 1.3438x over previous
//
#include <hip/hip_runtime.h>
#include <hip/hip_bf16.h>
#include <math.h>

// ---------------------------------------------------------------------------
// ConvFormer: T=8, Ci=1, Co=16, spatial 64^3.
//   k_prep:  repack k1 conv weights (fp32) + k3 MFMA weight frags (f16,
//            tap-paired: K=16 = 2 taps x 8 ci per half)
//   k1_qkv:  q/k/v 3x3x3 convs (fp32 math, f16 planar stores)
//   kstats16: per-plane sum/sumsq on f16 planar -> k_finstats: mean/rstd
//   k2_attn: MFMA gating (swapped-operand mfma_f32_16x16x16_f16), f16 reads,
//            writes u f16 interleaved [vox][ci] into d_out
//   k3_conv: final 16->16 conv, implicit GEMM, tile (4,4,64), ci-split
//            two-stage LDS (38KB), tap-paired MFMAs, fused stats
//   k_finstats; k4_norm: interleaved f16 y -> planar fp32 d_out
// ---------------------------------------------------------------------------

#define V18 (1 << 18)
#define SOFF (3 * (1 << 25))   // float offset of stats region in ws (legacy)

#define COMP(v, j) ((j) == 0 ? (v).x : (j) == 1 ? (v).y : (j) == 2 ? (v).z : (v).w)

typedef __attribute__((ext_vector_type(4))) _Float16 f16x4;
typedef __attribute__((ext_vector_type(8))) _Float16 f16x8;
typedef __attribute__((ext_vector_type(4))) float f32x4;

__device__ __forceinline__ float lrelu(float x) { return x > 0.f ? x : 0.2f * x; }
__device__ __forceinline__ float sigm(float x) {
  return __builtin_amdgcn_rcpf(1.f + __expf(-x));
}

__device__ __forceinline__ f32x4 mfma16(f16x4 a, f16x4 b, f32x4 c) {
  return __builtin_amdgcn_mfma_f32_16x16x16f16(a, b, c, 0, 0, 0);
}

// --------------------------------------------------------------------------
__global__ void k_prep(const float* __restrict__ Wq, const float* __restrict__ Wk,
                       const float* __restrict__ Wv, const float* __restrict__ Wf,
                       float* __restrict__ P) {
  int tid = threadIdx.x;
  for (int i = tid; i < 1344; i += 256) {        // [conv][co][28]
    int conv = i / 448, r = i % 448, co = r / 28, tap = r % 28;
    const float* W = conv == 0 ? Wq : conv == 1 ? Wk : Wv;
    P[i] = (tap < 27) ? W[co * 27 + tap] : 0.f;
  }
  // k3 A-frags: wf16[h][p][lane][j]; k=(lane>>4)*4+j; tp=k>>3; ci=h*8+(k&7);
  // tap = p*2+tp; element = Wf[co=lane&15][ci][tap] (0 if tap>=27)
  _Float16* wf16 = (_Float16*)(P + 1344);
  for (int i = tid; i < 7168; i += 256) {
    int h = i / 3584, r = i % 3584, p = r / 256, q_ = r & 255;
    int lane = q_ >> 2, j = q_ & 3;
    int co = lane & 15, kq = lane >> 4;
    int kk = kq * 4 + j, tp = kk >> 3, ci = h * 8 + (kk & 7), tap = p * 2 + tp;
    wf16[i] = (tap < 27) ? (_Float16)Wf[co * 432 + ci * 27 + tap] : (_Float16)0.f;
  }
}

// --------------------------------------------------------------------------
// k1: tile (z,y,x)=(4,4,64), 1024 voxels, 4 consecutive-x per thread.
__global__ __launch_bounds__(256) void k1_qkv(
    const float* __restrict__ c, const float* __restrict__ e,
    const float* __restrict__ pos, const float* __restrict__ P,
    const float* __restrict__ bq, const float* __restrict__ bk,
    const float* __restrict__ bv, _Float16* __restrict__ q,
    _Float16* __restrict__ k, _Float16* __restrict__ v) {
  __shared__ __align__(16) float se[2448];   // 6*6*68
  __shared__ __align__(16) float sc[2448];
  __shared__ __align__(16) float wl[1344];
  const int t = blockIdx.y;
  const int tile = blockIdx.x;               // 256 = 16z * 16y
  const int y0 = (tile & 15) * 4;
  const int z0 = (tile >> 4) * 4;
  for (int i = threadIdx.x; i < 1344; i += 256) wl[i] = P[i];
  const float* cin = c + t * V18;
  const float* ein = e + t * V18;
  for (int i = threadIdx.x; i < 2448; i += 256) {
    int lz = i / 408, r = i % 408, ly = r / 68, lx = r % 68;
    int gz = z0 + lz - 1, gy = y0 + ly - 1, gx = lx - 1;
    float pe = 0.f, pc = 0.f;
    if (lx < 66 && (unsigned)gz < 64u && (unsigned)gy < 64u && (unsigned)gx < 64u) {
      int gi = (gz << 12) + (gy << 6) + gx;
      float pv = pos[gi];
      pc = cin[gi] + pv;
      pe = ein[gi] + pv;
    }
    se[i] = pe;
    sc[i] = pc;
  }
  __syncthreads();

  const int lz = threadIdx.x >> 6, ly = (threadIdx.x >> 4) & 3,
            lx = (threadIdx.x & 15) * 4;
  const int gi = ((z0 + lz) << 12) + ((y0 + ly) << 6) + lx;

  // ---- pass 1: q (input e) ----
  {
    float xr[3][3][6];
#pragma unroll
    for (int dz = 0; dz < 3; ++dz)
#pragma unroll
      for (int dy = 0; dy < 3; ++dy) {
        int base = ((lz + dz) * 6 + (ly + dy)) * 68 + lx;
        float4 a = *(const float4*)&se[base];
        float2 b2 = *(const float2*)&se[base + 4];
        xr[dz][dy][0] = a.x; xr[dz][dy][1] = a.y; xr[dz][dy][2] = a.z;
        xr[dz][dy][3] = a.w; xr[dz][dy][4] = b2.x; xr[dz][dy][5] = b2.y;
      }
#pragma unroll 1
    for (int co = 0; co < 16; ++co) {
      float bias = bq[co];
      float4 acc = {bias, bias, bias, bias};
      const float* wp = &wl[co * 28];
#pragma unroll
      for (int tg = 0; tg < 7; ++tg) {
        float4 w4 = *(const float4*)&wp[tg * 4];
#pragma unroll
        for (int j = 0; j < 4; ++j) {
          const int tap = tg * 4 + j;
          if (tap < 27) {
            const int dz = tap / 9, dy = (tap / 3) % 3, dx = tap % 3;
            float w = COMP(w4, j);
            acc.x += w * xr[dz][dy][dx + 0];
            acc.y += w * xr[dz][dy][dx + 1];
            acc.z += w * xr[dz][dy][dx + 2];
            acc.w += w * xr[dz][dy][dx + 3];
          }
        }
      }
      f16x4 o = {(_Float16)acc.x, (_Float16)acc.y, (_Float16)acc.z, (_Float16)acc.w};
      *(f16x4*)&q[((t * 16 + co) << 18) + gi] = o;
    }
  }
  // ---- pass 2: k, v (input c) ----
  {
    float xr[3][3][6];
#pragma unroll
    for (int dz = 0; dz < 3; ++dz)
#pragma unroll
      for (int dy = 0; dy < 3; ++dy) {
        int base = ((lz + dz) * 6 + (ly + dy)) * 68 + lx;
        float4 a = *(const float4*)&sc[base];
        float2 b2 = *(const float2*)&sc[base + 4];
        xr[dz][dy][0] = a.x; xr[dz][dy][1] = a.y; xr[dz][dy][2] = a.z;
        xr[dz][dy][3] = a.w; xr[dz][dy][4] = b2.x; xr[dz][dy][5] = b2.y;
      }
#pragma unroll 1
    for (int co = 0; co < 16; ++co) {
      float bk_ = bk[co], bv_ = bv[co];
      float4 ak = {bk_, bk_, bk_, bk_};
      float4 av = {bv_, bv_, bv_, bv_};
      const float* wpk = &wl[448 + co * 28];
      const float* wpv = &wl[896 + co * 28];
#pragma unroll
      for (int tg = 0; tg < 7; ++tg) {
        float4 wk4 = *(const float4*)&wpk[tg * 4];
        float4 wv4 = *(const float4*)&wpv[tg * 4];
#pragma unroll
        for (int j = 0; j < 4; ++j) {
          const int tap = tg * 4 + j;
          if (tap < 27) {
            const int dz = tap / 9, dy = (tap / 3) % 3, dx = tap % 3;
            float wk_ = COMP(wk4, j), wv_ = COMP(wv4, j);
            ak.x += wk_ * xr[dz][dy][dx + 0];
            ak.y += wk_ * xr[dz][dy][dx + 1];
            ak.z += wk_ * xr[dz][dy][dx + 2];
            ak.w += wk_ * xr[dz][dy][dx + 3];
            av.x += wv_ * xr[dz][dy][dx + 0];
            av.y += wv_ * xr[dz][dy][dx + 1];
            av.z += wv_ * xr[dz][dy][dx + 2];
            av.w += wv_ * xr[dz][dy][dx + 3];
          }
        }
      }
      f16x4 ok = {(_Float16)ak.x, (_Float16)ak.y, (_Float16)ak.z, (_Float16)ak.w};
      f16x4 ov = {(_Float16)av.x, (_Float16)av.y, (_Float16)av.z, (_Float16)av.w};
      *(f16x4*)&k[((t * 16 + co) << 18) + gi] = ok;
      *(f16x4*)&v[((t * 16 + co) << 18) + gi] = ov;
    }
  }
}

// --------------------------------------------------------------------------
// kstats16: grid (8, 384); each block sums 32768 f16 of one plane.
__global__ __launch_bounds__(256) void kstats16(const _Float16* __restrict__ src,
                                                float* __restrict__ sums) {
  const int plane = blockIdx.y;
  const _Float16* sp = src + ((size_t)plane << 18) + (blockIdx.x << 15);
  float s = 0.f, s2 = 0.f;
#pragma unroll
  for (int j = 0; j < 16; ++j) {
    f16x8 val = *(const f16x8*)&sp[(j * 256 + threadIdx.x) * 8];
#pragma unroll
    for (int u_ = 0; u_ < 8; ++u_) {
      float x = (float)val[u_];
      s += x;
      s2 += x * x;
    }
  }
#pragma unroll
  for (int d = 32; d > 0; d >>= 1) {
    s += __shfl_xor(s, d);
    s2 += __shfl_xor(s2, d);
  }
  __shared__ float rs[8];
  const int wid = threadIdx.x >> 6;
  if ((threadIdx.x & 63) == 0) {
    rs[wid] = s;
    rs[4 + wid] = s2;
  }
  __syncthreads();
  if (threadIdx.x == 0) {
    atomicAdd(&sums[plane * 2], rs[0] + rs[1] + rs[2] + rs[3]);
    atomicAdd(&sums[plane * 2 + 1], rs[4] + rs[5] + rs[6] + rs[7]);
  }
}

// --------------------------------------------------------------------------
__global__ void k_finstats(const float* __restrict__ sums, float* __restrict__ mr,
                           int n, float invn) {
  int i = blockIdx.x * blockDim.x + threadIdx.x;
  if (i >= n) return;
  float m = sums[i * 2] * invn;
  float var = sums[i * 2 + 1] * invn - m * m;
  mr[i * 2] = m;
  mr[i * 2 + 1] = rsqrtf(fmaxf(var, 0.f) + 1e-5f);
}

// --------------------------------------------------------------------------
// k2: MFMA gating; f16 planar in, u f16 interleaved [vox][ci] out.
__global__ __launch_bounds__(256) void k2_attn(
    const _Float16* __restrict__ q, const _Float16* __restrict__ k,
    const _Float16* __restrict__ v, const float* __restrict__ Wa1,
    const float* __restrict__ Wa2, const float* __restrict__ Wa3,
    const float* __restrict__ mr, const float* __restrict__ ba1,
    const float* __restrict__ ba2, const float* __restrict__ ba3,
    _Float16* __restrict__ u) {
  const int lane = threadIdx.x & 63;
  const int wid = threadIdx.x >> 6;
  const int row = lane & 15;           // voxel-in-group / weight row (o)
  const int c0 = (lane >> 4) * 4;      // channel quad base
  const int vox = (blockIdx.x * 4 + wid) * 16 + row;

  f32x4 w1f = *(const f32x4*)&Wa1[row * 16 + c0];
  f32x4 w2f = *(const f32x4*)&Wa2[row * 16 + c0];
  f32x4 w3f = *(const f32x4*)&Wa3[row * 16 + c0];
  f16x4 wa1 = {(_Float16)w1f[0], (_Float16)w1f[1], (_Float16)w1f[2], (_Float16)w1f[3]};
  f16x4 wa2 = {(_Float16)w2f[0], (_Float16)w2f[1], (_Float16)w2f[2], (_Float16)w2f[3]};
  f16x4 wa3 = {(_Float16)w3f[0], (_Float16)w3f[1], (_Float16)w3f[2], (_Float16)w3f[3]};
  f32x4 b1q = *(const f32x4*)&ba1[c0];
  f32x4 b2q = *(const f32x4*)&ba2[c0];
  f32x4 b3q = *(const f32x4*)&ba3[c0];

  f32x4 A[8], acc[8];
  f16x4 qn[8];
#pragma unroll
  for (int t = 0; t < 8; ++t) {
    f32x4 s01 = *(const f32x4*)&mr[(t * 16 + c0) * 2];
    f32x4 s23 = *(const f32x4*)&mr[(t * 16 + c0) * 2 + 4];
    float x0 = lrelu(((float)q[((t * 16 + c0 + 0) << 18) + vox] - s01[0]) * s01[1]);
    float x1 = lrelu(((float)q[((t * 16 + c0 + 1) << 18) + vox] - s01[2]) * s01[3]);
    float x2 = lrelu(((float)q[((t * 16 + c0 + 2) << 18) + vox] - s23[0]) * s23[1]);
    float x3 = lrelu(((float)q[((t * 16 + c0 + 3) << 18) + vox] - s23[2]) * s23[3]);
    qn[t] = (f16x4){(_Float16)x0, (_Float16)x1, (_Float16)x2, (_Float16)x3};
    A[t] = mfma16(wa1, qn[t], b1q);
    acc[t] = (f32x4){0.f, 0.f, 0.f, 0.f};
  }
#pragma unroll 1
  for (int j = 0; j < 8; ++j) {
    f32x4 sk01 = *(const f32x4*)&mr[256 + (j * 16 + c0) * 2];
    f32x4 sk23 = *(const f32x4*)&mr[256 + (j * 16 + c0) * 2 + 4];
    f32x4 sv01 = *(const f32x4*)&mr[512 + (j * 16 + c0) * 2];
    f32x4 sv23 = *(const f32x4*)&mr[512 + (j * 16 + c0) * 2 + 4];
    float k0 = lrelu(((float)k[((j * 16 + c0 + 0) << 18) + vox] - sk01[0]) * sk01[1]);
    float k1 = lrelu(((float)k[((j * 16 + c0 + 1) << 18) + vox] - sk01[2]) * sk01[3]);
    float k2 = lrelu(((float)k[((j * 16 + c0 + 2) << 18) + vox] - sk23[0]) * sk23[1]);
    float k3 = lrelu(((float)k[((j * 16 + c0 + 3) << 18) + vox] - sk23[2]) * sk23[3]);
    f32x4 vnq;
    vnq[0] = lrelu(((float)v[((j * 16 + c0 + 0) << 18) + vox] - sv01[0]) * sv01[1]);
    vnq[1] = lrelu(((float)v[((j * 16 + c0 + 1) << 18) + vox] - sv01[2]) * sv01[3]);
    vnq[2] = lrelu(((float)v[((j * 16 + c0 + 2) << 18) + vox] - sv23[0]) * sv23[1]);
    vnq[3] = lrelu(((float)v[((j * 16 + c0 + 3) << 18) + vox] - sv23[2]) * sv23[3]);
    f16x4 knh = (f16x4){(_Float16)k0, (_Float16)k1, (_Float16)k2, (_Float16)k3};
    f32x4 B = mfma16(wa2, knh, b2q);
#pragma unroll
    for (int i = 0; i < 8; ++i) {
      f32x4 rel = A[i] + B;
      f16x4 rh = (f16x4){(_Float16)fmaxf(rel[0], 0.f), (_Float16)fmaxf(rel[1], 0.f),
                         (_Float16)fmaxf(rel[2], 0.f), (_Float16)fmaxf(rel[3], 0.f)};
      f32x4 s = mfma16(wa3, rh, b3q);
      acc[i][0] += sigm(s[0]) * vnq[0];
      acc[i][1] += sigm(s[1]) * vnq[1];
      acc[i][2] += sigm(s[2]) * vnq[2];
      acc[i][3] += sigm(s[3]) * vnq[3];
    }
  }
#pragma unroll
  for (int t = 0; t < 8; ++t) {
    f16x4 o = {(_Float16)(acc[t][0] + (float)qn[t][0]),
               (_Float16)(acc[t][1] + (float)qn[t][1]),
               (_Float16)(acc[t][2] + (float)qn[t][2]),
               (_Float16)(acc[t][3] + (float)qn[t][3])};
    *(f16x4*)&u[((size_t)t << 22) + (vox << 4) + c0] = o;
  }
}

// --------------------------------------------------------------------------
// k3: implicit-GEMM MFMA conv. Tile (4,4,64)=1024 vox, 4 waves (wave=z-slice),
// 16 groups/wave. ci-split: two stages of 8 channels, LDS [36row][66x][8ci]
// f16 (38KB). Tap-paired K=16 MFMA: k = tp*8+ci_l, tp=lane>>5.
__global__ __launch_bounds__(256) void k3_conv(
    const _Float16* __restrict__ u16, const _Float16* __restrict__ wf16,
    const float* __restrict__ bfv, _Float16* __restrict__ y16,
    float* __restrict__ fsums) {
  __shared__ __align__(16) _Float16 sx[36 * 66 * 8];  // 38016 B
  __shared__ float red[32];
  const int t = blockIdx.y;
  const int tile = blockIdx.x;      // 256 = 16z * 16y
  const int y0 = (tile & 15) * 4;
  const int z0 = (tile >> 4) * 4;
  const int tid = threadIdx.x;
  const int lane = tid & 63, zw = tid >> 6;

  if (tid < 32) red[tid] = 0.f;

  const int colv = lane & 15;
  const int tp = lane >> 5;
  const int ciq = ((lane >> 4) & 1) * 4;

  f32x4 bq = *(const f32x4*)&bfv[(lane >> 4) * 4];
  f32x4 acc[16];
#pragma unroll
  for (int g = 0; g < 16; ++g) acc[g] = bq;

  const _Float16* ubase = u16 + ((size_t)t << 22);

#pragma unroll 1
  for (int h = 0; h < 2; ++h) {
    __syncthreads();
    for (int i = tid; i < 2376; i += 256) {
      int rw = i / 66, xs = i % 66;
      int gz = z0 + rw / 6 - 1, gy = y0 + rw % 6 - 1, gx = xs - 1;
      f16x8 val = {};
      if ((unsigned)gz < 64u && (unsigned)gy < 64u && (unsigned)gx < 64u)
        val = *(const f16x8*)&ubase[(((gz << 12) + (gy << 6) + gx) << 4) + h * 8];
      *(f16x8*)&sx[(rw * 66 + xs) * 8] = val;
    }
    __syncthreads();

#pragma unroll
    for (int p = 0; p < 14; ++p) {
      f16x4 w = *(const f16x4*)&wf16[(h * 14 + p) * 256 + lane * 4];
      int tap = p * 2 + tp;
      if (tap > 26) tap = 26;          // pad pair; weights are zero
      const int dz = tap / 9, dy = (tap % 9) / 3, dx = tap % 3;
      const int base_p = (((zw + dz) * 6 + dy) * 66 + colv + dx) * 8 + ciq;
#pragma unroll
      for (int g = 0; g < 16; ++g) {
        f16x4 b = *(const f16x4*)&sx[base_p + ((g >> 2) * 66 + (g & 3) * 16) * 8];
        acc[g] = mfma16(w, b, acc[g]);
      }
    }
  }

  // store y (f16 interleaved) + fused stats
  float s[4] = {0.f, 0.f, 0.f, 0.f}, s2[4] = {0.f, 0.f, 0.f, 0.f};
  _Float16* ybase = y16 + ((size_t)t << 22);
#pragma unroll
  for (int g = 0; g < 16; ++g) {
    const int gvox = ((z0 + zw) << 12) + ((y0 + (g >> 2)) << 6) + (g & 3) * 16 + colv;
    f16x4 o = {(_Float16)acc[g][0], (_Float16)acc[g][1],
               (_Float16)acc[g][2], (_Float16)acc[g][3]};
    *(f16x4*)&ybase[(gvox << 4) + (lane >> 4) * 4] = o;
#pragma unroll
    for (int j = 0; j < 4; ++j) {
      s[j] += acc[g][j];
      s2[j] += acc[g][j] * acc[g][j];
    }
  }
#pragma unroll
  for (int d = 1; d < 16; d <<= 1)
#pragma unroll
    for (int j = 0; j < 4; ++j) {
      s[j] += __shfl_xor(s[j], d);
      s2[j] += __shfl_xor(s2[j], d);
    }
  if ((lane & 15) == 0) {
    const int co0 = (lane >> 4) * 4;
#pragma unroll
    for (int j = 0; j < 4; ++j) {
      atomicAdd(&red[(co0 + j) * 2], s[j]);
      atomicAdd(&red[(co0 + j) * 2 + 1], s2[j]);
    }
  }
  __syncthreads();
  if (tid < 32) atomicAdd(&fsums[t * 32 + tid], red[tid]);
}

// --------------------------------------------------------------------------
// k4: interleaved f16 y -> normalized planar fp32 out.
__global__ __launch_bounds__(256) void k4_norm(const _Float16* __restrict__ y16,
                                               const float* __restrict__ fmr,
                                               float* __restrict__ out) {
  const int t = blockIdx.x >> 8;            // 256 blocks per t
  const int vb = (blockIdx.x & 255) << 10;
  const _Float16* yb = y16 + ((size_t)t << 22);
  float* ob = out + ((size_t)t << 22);
  const float* f = fmr + t * 32;
#pragma unroll 1
  for (int it = 0; it < 4; ++it) {
    const int voxl = vb + it * 256 + threadIdx.x;
    f16x8 h0 = *(const f16x8*)&yb[voxl << 4];
    f16x8 h1 = *(const f16x8*)&yb[(voxl << 4) + 8];
#pragma unroll
    for (int co = 0; co < 8; ++co)
      ob[(co << 18) + voxl] = lrelu(((float)h0[co] - f[co * 2]) * f[co * 2 + 1]);
#pragma unroll
    for (int co = 0; co < 8; ++co)
      ob[((co + 8) << 18) + voxl] =
          lrelu(((float)h1[co] - f[(co + 8) * 2]) * f[(co + 8) * 2 + 1]);
  }
}

// --------------------------------------------------------------------------
extern "C" void kernel_launch(void* const* d_in, const int* in_sizes, int n_in,
                              void* d_out, int out_size, void* d_ws, size_t ws_size,
                              hipStream_t stream) {
  const float* c = (const float*)d_in[0];
  const float* e = (const float*)d_in[1];
  const float* pos = (const float*)d_in[2];
  const float* Wq = (const float*)d_in[3];
  const float* bq = (const float*)d_in[4];
  const float* Wk = (const float*)d_in[5];
  const float* bk = (const float*)d_in[6];
  const float* Wv = (const float*)d_in[7];
  const float* bv = (const float*)d_in[8];
  const float* Wa1 = (const float*)d_in[9];
  const float* ba1 = (const float*)d_in[10];
  const float* Wa2 = (const float*)d_in[11];
  const float* ba2 = (const float*)d_in[12];
  const float* Wa3 = (const float*)d_in[13];
  const float* ba3 = (const float*)d_in[14];
  const float* Wf = (const float*)d_in[15];
  const float* bf_ = (const float*)d_in[16];

  float* ws = (float*)d_ws;
  _Float16* q16 = (_Float16*)ws;             // 3 x 2^25 f16 (q,k,v contiguous)
  _Float16* k16 = q16 + (1 << 25);
  _Float16* v16 = q16 + (2 << 25);
  _Float16* y16 = (_Float16*)ws;             // aliases q16 (dead after k2)
  float* stats = ws + SOFF;                  // qkv sums: 768
  float* fsums = stats + 768;                // 256 (zeroed by memset)
  float* qkvmr = stats + 1024;               // 768
  float* fmr = stats + 1792;                 // 256
  float* P = stats + 2048;                   // k1 weights + wf16 frags
  _Float16* wf16 = (_Float16*)(P + 1344);
  _Float16* u16 = (_Float16*)d_out;

  hipMemsetAsync(stats, 0, 1024 * sizeof(float), stream);
  hipLaunchKernelGGL(k_prep, dim3(1), dim3(256), 0, stream, Wq, Wk, Wv, Wf, P);
  hipLaunchKernelGGL(k1_qkv, dim3(256, 8), dim3(256), 0, stream,
                     c, e, pos, P, bq, bk, bv, q16, k16, v16);
  hipLaunchKernelGGL(kstats16, dim3(8, 384), dim3(256), 0, stream, q16, stats);
  hipLaunchKernelGGL(k_finstats, dim3(2), dim3(256), 0, stream,
                     stats, qkvmr, 384, 1.f / 262144.f);
  hipLaunchKernelGGL(k2_attn, dim3(4096), dim3(256), 0, stream,
                     q16, k16, v16, Wa1, Wa2, Wa3, qkvmr, ba1, ba2, ba3, u16);
  hipLaunchKernelGGL(k3_conv, dim3(256, 8), dim3(256), 0, stream,
                     u16, wf16, bf_, y16, fsums);
  hipLaunchKernelGGL(k_finstats, dim3(1), dim3(256), 0, stream,
                     fsums, fmr, 128, 1.f / 262144.f);
  hipLaunchKernelGGL(k4_norm, dim3(2048), dim3(256), 0, stream, y16, fmr,
                     (float*)d_out);
}